// Round 1
// baseline (10054.544 us; speedup 1.0000x reference)
//
#include <hip/hip_runtime.h>
#include <hip/hip_bf16.h>
#include <math.h>

#define BB 64
#define TT 32
#define HH 512
#define H2 1024
#define H4 2048
#define SS 400

// workspace float offsets
#define OFF_E    0u                               // [T][B][H]   = 1048576 floats
#define OFF_TH   1048576u                         // [2][B][H]
#define OFF_TC   (OFF_TH + 2u*BB*HH)
#define OFF_XH   (OFF_TC + 2u*BB*HH)
#define OFF_XC   (OFF_XH + 2u*BB*HH)
#define OFF_G    (OFF_XC + 2u*BB*HH)              // [2ks][2br][B][4H] = 524288
#define OFF_TGT  (OFF_G + 4u*BB*H4)               // [2][B][H]
#define OFF_PACC (OFF_TGT + 2u*BB*HH)             // [2br*B*2sh][H] = 131072
#define OFF_PML  (OFF_PACC + 2u*BB*2u*HH)         // [256][2] (m,l)

__device__ __forceinline__ float sigm(float x){ return 1.f/(1.f+__expf(-x)); }

// ---- one-time: gather per-step embeddings E[t][b][:] ----
__global__ __launch_bounds__(128) void k_prep(const int* __restrict__ inp,
    const float* __restrict__ emb0, const float* __restrict__ wemb,
    float* __restrict__ ws){
  int n = blockIdx.x;              // 0..2047
  int t = n / BB, b = n % BB;
  const float* src = (t==0) ? (emb0 + (size_t)b*HH)
                            : (wemb + (size_t)inp[b*TT + (t-1)]*HH);
  float4* dst = (float4*)(ws + OFF_E + ((size_t)t*BB + b)*HH);
  dst[threadIdx.x] = ((const float4*)src)[threadIdx.x];
}

// ---- one-time: state init into slot 0 ----
__global__ __launch_bounds__(256) void k_init(const float* __restrict__ th0,
    const float* __restrict__ tc0, const float* __restrict__ xh0,
    const float* __restrict__ xc0, float* __restrict__ ws){
  int i = blockIdx.x*256 + threadIdx.x;   // 0..32767 (f4 index)
  int which = i >> 13;
  int off = i & 8191;
  const float* src = which==0?th0: which==1?tc0: which==2?xh0:xc0;
  float* dstb = which==0? ws+OFF_TH : which==1? ws+OFF_TC : which==2? ws+OFF_XH : ws+OFF_XC;
  ((float4*)dstb)[off] = ((const float4*)src)[off];
}

// ---- per step: gate GEMM partials. grid 256 = gct(32) x bg(4) x ks(2), 256 thr ----
__global__ __launch_bounds__(256) void k_gemm(const float* __restrict__ Wx,
    const float* __restrict__ Wh, float* __restrict__ ws,
    const float* __restrict__ oprev, int ostride, int t, int rs){
  __shared__ float lds[4][16][128];   // 32 KB: xe,xo,ht,hx for 16 batches x 128 k
  int tid = threadIdx.x;
  int lane = tid & 63, wave = tid >> 6;
  int blk = blockIdx.x;
  int gct = blk & 31, bg = (blk>>5)&3, ks = blk>>7;
  int gc = gct*64 + lane;
  int b0 = bg*16;
  float accx[4]={0,0,0,0}, acct[4]={0,0,0,0}, accxh[4]={0,0,0,0};
  const float* Eb  = ws + OFF_E  + (size_t)t*BB*HH;
  const float* THr = ws + OFF_TH + (size_t)rs*BB*HH;
  const float* XHr = ws + OFF_XH + (size_t)rs*BB*HH;
  for (int kc2=0; kc2<2; kc2++){
    int kc = ks*2 + kc2;
    #pragma unroll
    for (int i2=0;i2<8;i2++){
      int flat = tid + i2*256;          // 0..2047 f4
      int arr = flat >> 9;
      int rem = flat & 511;
      int bl = rem >> 5, k4 = rem & 31;
      int b = b0 + bl;
      const float* src;
      if (arr==0)      src = Eb  + (size_t)b*HH;
      else if (arr==1) src = oprev + (size_t)b*ostride;
      else if (arr==2) src = THr + (size_t)b*HH;
      else             src = XHr + (size_t)b*HH;
      float4 v = *(const float4*)(src + kc*128 + k4*4);
      *(float4*)&lds[arr][bl][k4*4] = v;
    }
    __syncthreads();
    for (int k4=0;k4<32;k4++){
      float4 xe[4], xo[4], ht[4], hx[4];
      #pragma unroll
      for (int i=0;i<4;i++){
        int bl = wave*4 + i;
        xe[i] = *(const float4*)&lds[0][bl][k4*4];
        xo[i] = *(const float4*)&lds[1][bl][k4*4];
        ht[i] = *(const float4*)&lds[2][bl][k4*4];
        hx[i] = *(const float4*)&lds[3][bl][k4*4];
      }
      int kb = kc*128 + k4*4;
      #pragma unroll
      for (int kk=0;kk<4;kk++){
        int k = kb + kk;
        float wx1 = Wx[(size_t)k*H4 + gc];
        float wx2 = Wx[(size_t)(HH + k)*H4 + gc];
        float wh  = Wh[(size_t)k*H4 + gc];
        #pragma unroll
        for (int i=0;i<4;i++){
          float e  = ((const float*)&xe[i])[kk];
          float o  = ((const float*)&xo[i])[kk];
          float h1 = ((const float*)&ht[i])[kk];
          float h2 = ((const float*)&hx[i])[kk];
          accx[i]  += e*wx1 + o*wx2;
          acct[i]  += h1*wh;
          accxh[i] += h2*wh;
        }
      }
    }
    __syncthreads();
  }
  #pragma unroll
  for (int i=0;i<4;i++){
    int b = b0 + wave*4 + i;
    ws[OFF_G + (((size_t)ks*2 + 0)*BB + b)*H4 + gc] = accx[i] + acct[i];
    ws[OFF_G + (((size_t)ks*2 + 1)*BB + b)*H4 + gc] = accx[i] + accxh[i];
  }
}

// ---- per step: sum partials + LSTM pointwise. grid 128 x 256 ----
__global__ __launch_bounds__(256) void k_lstm(float* __restrict__ ws,
    const float* __restrict__ bias, int rs){
  int gid = blockIdx.x*256 + threadIdx.x;   // 0..32767
  int b = gid >> 9, j = gid & 511;
  int wsl = rs ^ 1;
  #pragma unroll
  for (int br=0;br<2;br++){
    float g[4];
    #pragma unroll
    for (int gi=0;gi<4;gi++){
      int gcol = gi*HH + j;
      g[gi] = ws[OFF_G + (((size_t)0*2+br)*BB + b)*H4 + gcol]
            + ws[OFF_G + (((size_t)1*2+br)*BB + b)*H4 + gcol]
            + bias[gcol];
    }
    size_t hoff = (br? OFF_XH : OFF_TH), coff = (br? OFF_XC : OFF_TC);
    float cold = ws[coff + (size_t)rs*BB*HH + (size_t)b*HH + j];
    float cn = sigm(g[1])*cold + sigm(g[0])*tanhf(g[2]);
    float hn = sigm(g[3])*tanhf(cn);
    ws[coff + (size_t)wsl*BB*HH + (size_t)b*HH + j] = cn;
    ws[hoff + (size_t)wsl*BB*HH + (size_t)b*HH + j] = hn;
  }
}

// ---- per step: targets = [th; xh] @ W_in. grid 256 = rt(32) x ct(8), 256 thr ----
__global__ __launch_bounds__(256) void k_tgt(const float* __restrict__ W_in,
    float* __restrict__ ws, int wsl){
  int lane = threadIdx.x & 63, wave = threadIdx.x >> 6;
  int rt = blockIdx.x >> 3, ct = blockIdx.x & 7;
  int row = rt*4 + wave;                 // 0..127
  int branch = row >> 6, b = row & 63;
  const float* hrow = ws + (branch? OFF_XH : OFF_TH) + (size_t)wsl*BB*HH + (size_t)b*HH;
  int c = ct*64 + lane;
  float acc = 0.f;
  #pragma unroll 4
  for (int k=0;k<HH;k++) acc += hrow[k] * W_in[(size_t)k*HH + c];
  ws[OFF_TGT + (size_t)row*HH + c] = acc;
}

// ---- per step: flash attention partial. grid 256 = (sh,b,branch), 256 thr ----
__global__ __launch_bounds__(256) void k_attn(const float* __restrict__ tree_ctx,
    const float* __restrict__ text_ctx, float* __restrict__ ws){
  int blk = blockIdx.x;
  int branch = blk & 1, b = (blk>>1)&63, sh = blk>>7;
  int tid = threadIdx.x, lane = tid & 63, wave = tid >> 6;
  __shared__ float tgt_s[512];
  __shared__ float sc[2][4];
  if (tid < 128)
    ((float4*)tgt_s)[tid] = ((const float4*)(ws + OFF_TGT + (size_t)(branch*64+b)*HH))[tid];
  __syncthreads();
  const float* ctx = (branch? text_ctx : tree_ctx) + (size_t)b*SS*HH;
  int s0 = sh*200;
  float m = -INFINITY, l = 0.f, acc0 = 0.f, acc1 = 0.f;
  int h0 = tid*2;
  for (int tile=0; tile<50; tile++){
    int s = s0 + tile*4 + wave;
    const float* crow = ctx + (size_t)s*HH + lane*8;
    float4 ca = *(const float4*)crow;
    float4 cb = *(const float4*)(crow+4);
    float4 ta = *(const float4*)&tgt_s[lane*8];
    float4 tb = *(const float4*)&tgt_s[lane*8+4];
    float p = ca.x*ta.x + ca.y*ta.y + ca.z*ta.z + ca.w*ta.w
            + cb.x*tb.x + cb.y*tb.y + cb.z*tb.z + cb.w*tb.w;
    #pragma unroll
    for (int off=32; off; off>>=1) p += __shfl_xor(p, off, 64);
    if (lane==0) sc[tile&1][wave] = p;
    __syncthreads();
    float sv0 = sc[tile&1][0], sv1 = sc[tile&1][1];
    float sv2 = sc[tile&1][2], sv3 = sc[tile&1][3];
    float tm = fmaxf(fmaxf(sv0,sv1), fmaxf(sv2,sv3));
    float mn = fmaxf(m, tm);
    float scale = __expf(m - mn);
    float p0 = __expf(sv0-mn), p1 = __expf(sv1-mn);
    float p2 = __expf(sv2-mn), p3 = __expf(sv3-mn);
    m = mn;
    l = l*scale + (p0+p1+p2+p3);
    const float* c0 = ctx + (size_t)(s0 + tile*4)*HH + h0;
    float2 v0 = *(const float2*)c0;
    float2 v1 = *(const float2*)(c0 + HH);
    float2 v2 = *(const float2*)(c0 + 2*HH);
    float2 v3 = *(const float2*)(c0 + 3*HH);
    acc0 = acc0*scale + p0*v0.x + p1*v1.x + p2*v2.x + p3*v3.x;
    acc1 = acc1*scale + p0*v0.y + p1*v1.y + p2*v2.y + p3*v3.y;
  }
  int pidx = (branch*64 + b)*2 + sh;
  ws[OFF_PACC + (size_t)pidx*HH + h0]   = acc0;
  ws[OFF_PACC + (size_t)pidx*HH + h0+1] = acc1;
  if (tid==0){ ws[OFF_PML + pidx*2] = m; ws[OFF_PML + pidx*2 + 1] = l; }
}

// ---- per step: merge partials + out = tanh(combined @ W_out). grid 128 ----
__global__ __launch_bounds__(256) void k_out(const float* __restrict__ W_out,
    const float* __restrict__ ws, float* __restrict__ dout, int t, int wsl){
  int lane = threadIdx.x & 63, wave = threadIdx.x >> 6;
  int bt = blockIdx.x >> 3, ct = blockIdx.x & 7;
  int b = bt*4 + wave;
  int c = ct*64 + lane;
  float ce[2][2];
  #pragma unroll
  for (int br=0;br<2;br++){
    int p0 = (br*64 + b)*2;
    float m0 = ws[OFF_PML + p0*2],   l0 = ws[OFF_PML + p0*2+1];
    float m1 = ws[OFF_PML + p0*2+2], l1 = ws[OFF_PML + p0*2+3];
    float M = fmaxf(m0,m1);
    float e0 = __expf(m0-M), e1 = __expf(m1-M);
    float L = l0*e0 + l1*e1;
    ce[br][0] = e0/L; ce[br][1] = e1/L;
  }
  float acc = 0.f;
  const float* pa = ws + OFF_PACC;
  #pragma unroll 4
  for (int k=0;k<HH;k++){
    float comb = pa[(size_t)(b*2+0)*HH + k]*ce[0][0] + pa[(size_t)(b*2+1)*HH + k]*ce[0][1];
    acc += comb * W_out[(size_t)k*HH + c];
  }
  #pragma unroll 4
  for (int k=0;k<HH;k++){
    float comb = pa[(size_t)((64+b)*2+0)*HH + k]*ce[1][0] + pa[(size_t)((64+b)*2+1)*HH + k]*ce[1][1];
    acc += comb * W_out[(size_t)(HH + k)*HH + c];
  }
  const float* th = ws + OFF_TH + (size_t)wsl*BB*HH + (size_t)b*HH;
  const float* xh = ws + OFF_XH + (size_t)wsl*BB*HH + (size_t)b*HH;
  #pragma unroll 4
  for (int k=0;k<HH;k++) acc += th[k] * W_out[(size_t)(H2 + k)*HH + c];
  #pragma unroll 4
  for (int k=0;k<HH;k++) acc += xh[k] * W_out[(size_t)(H2 + HH + k)*HH + c];
  dout[((size_t)b*TT + t)*HH + c] = tanhf(acc);
}

extern "C" void kernel_launch(void* const* d_in, const int* in_sizes, int n_in,
                              void* d_out, int out_size, void* d_ws, size_t ws_size,
                              hipStream_t stream){
  const int*   inp   = (const int*)  d_in[0];
  const float* emb0  = (const float*)d_in[1];
  const float* out0  = (const float*)d_in[2];
  const float* th0   = (const float*)d_in[3];
  const float* tc0   = (const float*)d_in[4];
  const float* trctx = (const float*)d_in[5];
  const float* xh0   = (const float*)d_in[6];
  const float* xc0   = (const float*)d_in[7];
  const float* txctx = (const float*)d_in[8];
  const float* wemb  = (const float*)d_in[9];
  const float* Wx    = (const float*)d_in[10];
  const float* Wh    = (const float*)d_in[11];
  const float* bias  = (const float*)d_in[12];
  const float* W_in  = (const float*)d_in[13];
  const float* W_out = (const float*)d_in[14];
  float* ws  = (float*)d_ws;
  float* out = (float*)d_out;

  hipLaunchKernelGGL(k_prep, dim3(TT*BB), dim3(128), 0, stream, inp, emb0, wemb, ws);
  hipLaunchKernelGGL(k_init, dim3(128), dim3(256), 0, stream, th0, tc0, xh0, xc0, ws);
  for (int t=0; t<TT; t++){
    int rs = t & 1, wsl = rs ^ 1;
    const float* oprev = (t==0) ? out0 : (out + (size_t)(t-1)*HH);
    int ostride = (t==0) ? HH : TT*HH;
    hipLaunchKernelGGL(k_gemm, dim3(256), dim3(256), 0, stream, Wx, Wh, ws, oprev, ostride, t, rs);
    hipLaunchKernelGGL(k_lstm, dim3(128), dim3(256), 0, stream, ws, bias, rs);
    hipLaunchKernelGGL(k_tgt,  dim3(256), dim3(256), 0, stream, W_in, ws, wsl);
    hipLaunchKernelGGL(k_attn, dim3(256), dim3(256), 0, stream, trctx, txctx, ws);
    hipLaunchKernelGGL(k_out,  dim3(128), dim3(256), 0, stream, W_out, ws, out, t, wsl);
  }
}

// Round 2
// 6239.801 us; speedup vs baseline: 1.6114x; 1.6114x over previous
//
#include <hip/hip_runtime.h>
#include <hip/hip_bf16.h>
#include <math.h>

#define BB 64
#define TT 32
#define HH 512
#define H2 1024
#define H4 2048
#define SS 400

// workspace float offsets
#define OFF_E    0u                               // [T][B][H]   = 1048576 floats
#define OFF_TH   1048576u                         // [2][B][H]
#define OFF_TC   (OFF_TH + 2u*BB*HH)
#define OFF_XH   (OFF_TC + 2u*BB*HH)
#define OFF_XC   (OFF_XH + 2u*BB*HH)
#define OFF_G    (OFF_XC + 2u*BB*HH)              // [2ks][2br][B][4H] = 524288
#define OFF_TGT  (OFF_G + 4u*BB*H4)               // [2][B][H]
#define OFF_PACC (OFF_TGT + 2u*BB*HH)             // [2br*B*2sh][H] = 131072
#define OFF_PML  (OFF_PACC + 2u*BB*2u*HH)         // [256][2] (m,l)
// k_out partials alias the (already-consumed) gate buffer: [8ks][64b][512c]
#define OFF_PART OFF_G

__device__ __forceinline__ float sigm(float x){ return 1.f/(1.f+__expf(-x)); }

// ---- one-time: gather per-step embeddings E[t][b][:] ----
__global__ __launch_bounds__(128) void k_prep(const int* __restrict__ inp,
    const float* __restrict__ emb0, const float* __restrict__ wemb,
    float* __restrict__ ws){
  int n = blockIdx.x;              // 0..2047
  int t = n / BB, b = n % BB;
  const float* src = (t==0) ? (emb0 + (size_t)b*HH)
                            : (wemb + (size_t)inp[b*TT + (t-1)]*HH);
  float4* dst = (float4*)(ws + OFF_E + ((size_t)t*BB + b)*HH);
  dst[threadIdx.x] = ((const float4*)src)[threadIdx.x];
}

// ---- one-time: state init into slot 0 ----
__global__ __launch_bounds__(256) void k_init(const float* __restrict__ th0,
    const float* __restrict__ tc0, const float* __restrict__ xh0,
    const float* __restrict__ xc0, float* __restrict__ ws){
  int i = blockIdx.x*256 + threadIdx.x;   // 0..32767 (f4 index)
  int which = i >> 13;
  int off = i & 8191;
  const float* src = which==0?th0: which==1?tc0: which==2?xh0:xc0;
  float* dstb = which==0? ws+OFF_TH : which==1? ws+OFF_TC : which==2? ws+OFF_XH : ws+OFF_XC;
  ((float4*)dstb)[off] = ((const float4*)src)[off];
}

// ---- per step: gate GEMM partials. grid 256 = gct(32) x bg(4) x ks(2), 256 thr ----
__global__ __launch_bounds__(256) void k_gemm(const float* __restrict__ Wx,
    const float* __restrict__ Wh, float* __restrict__ ws,
    const float* __restrict__ oprev, int ostride, int t, int rs){
  __shared__ float lds[4][16][128];   // 32 KB: xe,xo,ht,hx for 16 batches x 128 k
  int tid = threadIdx.x;
  int lane = tid & 63, wave = tid >> 6;
  int blk = blockIdx.x;
  int gct = blk & 31, bg = (blk>>5)&3, ks = blk>>7;
  int gc = gct*64 + lane;
  int b0 = bg*16;
  float accx[4]={0,0,0,0}, acct[4]={0,0,0,0}, accxh[4]={0,0,0,0};
  const float* Eb  = ws + OFF_E  + (size_t)t*BB*HH;
  const float* THr = ws + OFF_TH + (size_t)rs*BB*HH;
  const float* XHr = ws + OFF_XH + (size_t)rs*BB*HH;
  for (int kc2=0; kc2<2; kc2++){
    int kc = ks*2 + kc2;
    #pragma unroll
    for (int i2=0;i2<8;i2++){
      int flat = tid + i2*256;          // 0..2047 f4
      int arr = flat >> 9;
      int rem = flat & 511;
      int bl = rem >> 5, k4 = rem & 31;
      int b = b0 + bl;
      const float* src;
      if (arr==0)      src = Eb  + (size_t)b*HH;
      else if (arr==1) src = oprev + (size_t)b*ostride;
      else if (arr==2) src = THr + (size_t)b*HH;
      else             src = XHr + (size_t)b*HH;
      float4 v = *(const float4*)(src + kc*128 + k4*4);
      *(float4*)&lds[arr][bl][k4*4] = v;
    }
    __syncthreads();
    for (int k4=0;k4<32;k4++){
      float4 xe[4], xo[4], ht[4], hx[4];
      #pragma unroll
      for (int i=0;i<4;i++){
        int bl = wave*4 + i;
        xe[i] = *(const float4*)&lds[0][bl][k4*4];
        xo[i] = *(const float4*)&lds[1][bl][k4*4];
        ht[i] = *(const float4*)&lds[2][bl][k4*4];
        hx[i] = *(const float4*)&lds[3][bl][k4*4];
      }
      int kb = kc*128 + k4*4;
      #pragma unroll
      for (int kk=0;kk<4;kk++){
        int k = kb + kk;
        float wx1 = Wx[(size_t)k*H4 + gc];
        float wx2 = Wx[(size_t)(HH + k)*H4 + gc];
        float wh  = Wh[(size_t)k*H4 + gc];
        #pragma unroll
        for (int i=0;i<4;i++){
          float e  = ((const float*)&xe[i])[kk];
          float o  = ((const float*)&xo[i])[kk];
          float h1 = ((const float*)&ht[i])[kk];
          float h2 = ((const float*)&hx[i])[kk];
          accx[i]  += e*wx1 + o*wx2;
          acct[i]  += h1*wh;
          accxh[i] += h2*wh;
        }
      }
    }
    __syncthreads();
  }
  #pragma unroll
  for (int i=0;i<4;i++){
    int b = b0 + wave*4 + i;
    ws[OFF_G + (((size_t)ks*2 + 0)*BB + b)*H4 + gc] = accx[i] + acct[i];
    ws[OFF_G + (((size_t)ks*2 + 1)*BB + b)*H4 + gc] = accx[i] + accxh[i];
  }
}

// ---- per step: sum partials + LSTM pointwise. grid 128 x 256 ----
__global__ __launch_bounds__(256) void k_lstm(float* __restrict__ ws,
    const float* __restrict__ bias, int rs){
  int gid = blockIdx.x*256 + threadIdx.x;   // 0..32767
  int b = gid >> 9, j = gid & 511;
  int wsl = rs ^ 1;
  #pragma unroll
  for (int br=0;br<2;br++){
    float g[4];
    #pragma unroll
    for (int gi=0;gi<4;gi++){
      int gcol = gi*HH + j;
      g[gi] = ws[OFF_G + (((size_t)0*2+br)*BB + b)*H4 + gcol]
            + ws[OFF_G + (((size_t)1*2+br)*BB + b)*H4 + gcol]
            + bias[gcol];
    }
    size_t hoff = (br? OFF_XH : OFF_TH), coff = (br? OFF_XC : OFF_TC);
    float cold = ws[coff + (size_t)rs*BB*HH + (size_t)b*HH + j];
    float cn = sigm(g[1])*cold + sigm(g[0])*tanhf(g[2]);
    float hn = sigm(g[3])*tanhf(cn);
    ws[coff + (size_t)wsl*BB*HH + (size_t)b*HH + j] = cn;
    ws[hoff + (size_t)wsl*BB*HH + (size_t)b*HH + j] = hn;
  }
}

// ---- per step: targets = [th; xh] @ W_in. grid 256 = rt(32) x ct(8), 256 thr ----
__global__ __launch_bounds__(256) void k_tgt(const float* __restrict__ W_in,
    float* __restrict__ ws, int wsl){
  int lane = threadIdx.x & 63, wave = threadIdx.x >> 6;
  int rt = blockIdx.x >> 3, ct = blockIdx.x & 7;
  int row = rt*4 + wave;                 // 0..127
  int branch = row >> 6, b = row & 63;
  const float* hrow = ws + (branch? OFF_XH : OFF_TH) + (size_t)wsl*BB*HH + (size_t)b*HH;
  int c = ct*64 + lane;
  float acc = 0.f;
  #pragma unroll 4
  for (int k=0;k<HH;k++) acc += hrow[k] * W_in[(size_t)k*HH + c];
  ws[OFF_TGT + (size_t)row*HH + c] = acc;
}

// ---- per step: flash attention partial. grid 256 = (sh,b,branch), 256 thr ----
__global__ __launch_bounds__(256) void k_attn(const float* __restrict__ tree_ctx,
    const float* __restrict__ text_ctx, float* __restrict__ ws){
  int blk = blockIdx.x;
  int branch = blk & 1, b = (blk>>1)&63, sh = blk>>7;
  int tid = threadIdx.x, lane = tid & 63, wave = tid >> 6;
  __shared__ float tgt_s[512];
  __shared__ float sc[2][4];
  if (tid < 128)
    ((float4*)tgt_s)[tid] = ((const float4*)(ws + OFF_TGT + (size_t)(branch*64+b)*HH))[tid];
  __syncthreads();
  const float* ctx = (branch? text_ctx : tree_ctx) + (size_t)b*SS*HH;
  int s0 = sh*200;
  float m = -INFINITY, l = 0.f, acc0 = 0.f, acc1 = 0.f;
  int h0 = tid*2;
  for (int tile=0; tile<50; tile++){
    int s = s0 + tile*4 + wave;
    const float* crow = ctx + (size_t)s*HH + lane*8;
    float4 ca = *(const float4*)crow;
    float4 cb = *(const float4*)(crow+4);
    float4 ta = *(const float4*)&tgt_s[lane*8];
    float4 tb = *(const float4*)&tgt_s[lane*8+4];
    float p = ca.x*ta.x + ca.y*ta.y + ca.z*ta.z + ca.w*ta.w
            + cb.x*tb.x + cb.y*tb.y + cb.z*tb.z + cb.w*tb.w;
    #pragma unroll
    for (int off=32; off; off>>=1) p += __shfl_xor(p, off, 64);
    if (lane==0) sc[tile&1][wave] = p;
    __syncthreads();
    float sv0 = sc[tile&1][0], sv1 = sc[tile&1][1];
    float sv2 = sc[tile&1][2], sv3 = sc[tile&1][3];
    float tm = fmaxf(fmaxf(sv0,sv1), fmaxf(sv2,sv3));
    float mn = fmaxf(m, tm);
    float scale = __expf(m - mn);
    float p0 = __expf(sv0-mn), p1 = __expf(sv1-mn);
    float p2 = __expf(sv2-mn), p3 = __expf(sv3-mn);
    m = mn;
    l = l*scale + (p0+p1+p2+p3);
    const float* c0 = ctx + (size_t)(s0 + tile*4)*HH + h0;
    float2 v0 = *(const float2*)c0;
    float2 v1 = *(const float2*)(c0 + HH);
    float2 v2 = *(const float2*)(c0 + 2*HH);
    float2 v3 = *(const float2*)(c0 + 3*HH);
    acc0 = acc0*scale + p0*v0.x + p1*v1.x + p2*v2.x + p3*v3.x;
    acc1 = acc1*scale + p0*v0.y + p1*v1.y + p2*v2.y + p3*v3.y;
  }
  int pidx = (branch*64 + b)*2 + sh;
  ws[OFF_PACC + (size_t)pidx*HH + h0]   = acc0;
  ws[OFF_PACC + (size_t)pidx*HH + h0+1] = acc1;
  if (tid==0){ ws[OFF_PML + pidx*2] = m; ws[OFF_PML + pidx*2 + 1] = l; }
}

// ---- per step: split-K GEMM for out = combined @ W_out (partials).
// grid 256 = ct(8) x bg(4) x ks(8). Each block: K-slice of 256, 16 batches,
// 64 cols. combined slice built directly into LDS (attn merge or th/xh copy).
__global__ __launch_bounds__(256) void k_outB(const float* __restrict__ W_out,
    float* __restrict__ ws, int wsl){
  __shared__ float comb_s[16][256];   // 16 KB
  __shared__ float ce_s[16][2];
  int tid = threadIdx.x, lane = tid & 63, wave = tid >> 6;
  int blk = blockIdx.x;
  int ct = blk & 7, bg = (blk>>3)&3, ks = blk>>5;   // ks 0..7
  int b0 = bg*16;
  int k0 = ks*256;
  int sec = ks >> 1;            // 0:tree 1:text 2:th 3:xh (512-aligned sections)
  int kk0 = (ks & 1)*256;       // offset within section
  int c = ct*64 + lane;

  if (sec < 2){
    if (tid < 16){
      int b = b0 + tid;
      int p0 = (sec*64 + b)*2;
      float m0 = ws[OFF_PML + p0*2],     l0 = ws[OFF_PML + p0*2+1];
      float m1 = ws[OFF_PML + (p0+1)*2], l1 = ws[OFF_PML + (p0+1)*2+1];
      float M = fmaxf(m0, m1);
      float e0 = __expf(m0-M), e1 = __expf(m1-M);
      float L = l0*e0 + l1*e1;
      ce_s[tid][0] = e0/L; ce_s[tid][1] = e1/L;
    }
    __syncthreads();
  }
  // stage combined[b0..b0+15][k0..k0+255] into LDS (4 float4 per thread)
  #pragma unroll
  for (int i=0;i<4;i++){
    int flat = tid + i*256;       // 0..1023 f4 index
    int row = flat >> 6;          // 0..15
    int q   = flat & 63;          // f4 within row
    int b = b0 + row;
    int h = kk0 + q*4;
    float4 v;
    if (sec < 2){
      int p0 = (sec*64 + b)*2;
      float4 a0 = *(const float4*)(ws + OFF_PACC + (size_t)p0*HH + h);
      float4 a1 = *(const float4*)(ws + OFF_PACC + (size_t)(p0+1)*HH + h);
      float c0 = ce_s[row][0], c1 = ce_s[row][1];
      v.x = a0.x*c0 + a1.x*c1; v.y = a0.y*c0 + a1.y*c1;
      v.z = a0.z*c0 + a1.z*c1; v.w = a0.w*c0 + a1.w*c1;
    } else {
      size_t hoff = (sec==2 ? OFF_TH : OFF_XH) + (size_t)wsl*BB*HH;
      v = *(const float4*)(ws + hoff + (size_t)b*HH + h);
    }
    *(float4*)&comb_s[row][q*4] = v;
  }
  __syncthreads();

  float acc[4] = {0,0,0,0};
  #pragma unroll 4
  for (int k=0;k<256;k++){
    float wv = W_out[(size_t)(k0+k)*HH + c];
    #pragma unroll
    for (int i=0;i<4;i++) acc[i] += comb_s[wave*4+i][k]*wv;
  }
  #pragma unroll
  for (int i=0;i<4;i++){
    int b = b0 + wave*4 + i;
    ws[OFF_PART + ((size_t)ks*BB + b)*HH + c] = acc[i];
  }
}

// ---- per step: reduce 8 partials + tanh + store. grid 32 x 256 ----
__global__ __launch_bounds__(256) void k_outC(const float* __restrict__ ws,
    float* __restrict__ dout, int t){
  int gid = blockIdx.x*256 + threadIdx.x;   // 0..8191 f4 indices
  int b = gid >> 7, cq = gid & 127;
  int c0 = cq*4;
  float4 s = {0,0,0,0};
  #pragma unroll
  for (int ks=0;ks<8;ks++){
    float4 p = *(const float4*)(ws + OFF_PART + ((size_t)ks*BB + b)*HH + c0);
    s.x += p.x; s.y += p.y; s.z += p.z; s.w += p.w;
  }
  float4 o;
  o.x = tanhf(s.x); o.y = tanhf(s.y); o.z = tanhf(s.z); o.w = tanhf(s.w);
  *(float4*)(dout + ((size_t)b*TT + t)*HH + c0) = o;
}

extern "C" void kernel_launch(void* const* d_in, const int* in_sizes, int n_in,
                              void* d_out, int out_size, void* d_ws, size_t ws_size,
                              hipStream_t stream){
  const int*   inp   = (const int*)  d_in[0];
  const float* emb0  = (const float*)d_in[1];
  const float* out0  = (const float*)d_in[2];
  const float* th0   = (const float*)d_in[3];
  const float* tc0   = (const float*)d_in[4];
  const float* trctx = (const float*)d_in[5];
  const float* xh0   = (const float*)d_in[6];
  const float* xc0   = (const float*)d_in[7];
  const float* txctx = (const float*)d_in[8];
  const float* wemb  = (const float*)d_in[9];
  const float* Wx    = (const float*)d_in[10];
  const float* Wh    = (const float*)d_in[11];
  const float* bias  = (const float*)d_in[12];
  const float* W_in  = (const float*)d_in[13];
  const float* W_out = (const float*)d_in[14];
  float* ws  = (float*)d_ws;
  float* out = (float*)d_out;

  hipLaunchKernelGGL(k_prep, dim3(TT*BB), dim3(128), 0, stream, inp, emb0, wemb, ws);
  hipLaunchKernelGGL(k_init, dim3(128), dim3(256), 0, stream, th0, tc0, xh0, xc0, ws);
  for (int t=0; t<TT; t++){
    int rs = t & 1, wsl = rs ^ 1;
    const float* oprev = (t==0) ? out0 : (out + (size_t)(t-1)*HH);
    int ostride = (t==0) ? HH : TT*HH;
    hipLaunchKernelGGL(k_gemm, dim3(256), dim3(256), 0, stream, Wx, Wh, ws, oprev, ostride, t, rs);
    hipLaunchKernelGGL(k_lstm, dim3(128), dim3(256), 0, stream, ws, bias, rs);
    hipLaunchKernelGGL(k_tgt,  dim3(256), dim3(256), 0, stream, W_in, ws, wsl);
    hipLaunchKernelGGL(k_attn, dim3(256), dim3(256), 0, stream, trctx, txctx, ws);
    hipLaunchKernelGGL(k_outB, dim3(256), dim3(256), 0, stream, W_out, ws, wsl);
    hipLaunchKernelGGL(k_outC, dim3(32),  dim3(256), 0, stream, ws, out, t);
  }
}

// Round 3
// 3490.988 us; speedup vs baseline: 2.8801x; 1.7874x over previous
//
#include <hip/hip_runtime.h>
#include <hip/hip_bf16.h>
#include <math.h>

#define BB 64
#define TT 32
#define HH 512
#define H2 1024
#define H4 2048
#define SS 400

// ---- workspace layout (float offsets) ----
#define OFF_WT_HI 0u          // WT hi plane: [2048 n][1536 k] bf16 = 1572864 floats
#define OFF_WT_LO 1572864u
#define OFF_EH    3145728u    // E hi: [32][64][512] bf16 = 524288 floats
#define OFF_EL    3670016u
#define OFF_OH    4194304u    // O planes [64][512] bf16
#define OFF_OL    4210688u
#define OFF_HHP   4227072u    // h planes [2br][64][512] bf16
#define OFF_HLP   4259840u
#define OFF_TC    4292608u    // fp32 [2 slot][64][512]
#define OFF_XC    4358144u
#define OFF_TH    4423680u    // fp32 [2 slot][64][512]
#define OFF_XH    4489216u
#define OFF_G     4554752u    // [8ks][128][2048] fp32 = 2097152
#define OFF_TGT   6651904u    // [2][64][512]
#define OFF_PACC  6717440u    // [256][512]
#define OFF_PML   6848512u    // [256][2]
#define OFF_PART  OFF_G       // k_out partials alias consumed G

typedef short bf16x8 __attribute__((ext_vector_type(8)));
typedef float f32x4  __attribute__((ext_vector_type(4)));

__device__ __forceinline__ float sigm(float x){ return 1.f/(1.f+__expf(-x)); }

__device__ __forceinline__ unsigned short bf_rn(float x){
  unsigned int u = __float_as_uint(x);
  return (unsigned short)((u + 0x7fffu + ((u>>16)&1u)) >> 16);
}
__device__ __forceinline__ void split2(float x, unsigned short &h, unsigned short &l){
  h = bf_rn(x);
  float hf = __uint_as_float(((unsigned int)h)<<16);
  l = bf_rn(x - hf);
}

// ---- one-time: transpose W=[Wx;Wh] (1536x2048) -> WT[n][k] hi/lo bf16 ----
__global__ __launch_bounds__(256) void k_wprep(const float* __restrict__ Wx,
    const float* __restrict__ Wh, unsigned short* __restrict__ wt_hi,
    unsigned short* __restrict__ wt_lo){
  __shared__ float lds[64][68];
  int bk = blockIdx.x >> 5, bn = blockIdx.x & 31;
  int k0 = bk*64, n0 = bn*64;
  int tid = threadIdx.x;
  #pragma unroll
  for (int i=0;i<4;i++){
    int flat = tid + i*256;          // 0..1023 f4
    int k = flat >> 4, nq = flat & 15;
    int kg = k0 + k;
    const float* srow = (kg < 1024) ? Wx + (size_t)kg*H4 : Wh + (size_t)(kg-1024)*H4;
    float4 v = *(const float4*)(srow + n0 + nq*4);
    *(float4*)&lds[k][nq*4] = v;
  }
  __syncthreads();
  #pragma unroll
  for (int i=0;i<2;i++){
    int flat = tid + i*256;          // 0..511
    int n = flat >> 3, k8 = flat & 7;
    ushort4 h0, h1, l0, l1;
    unsigned short h[8], l[8];
    #pragma unroll
    for (int j=0;j<8;j++) split2(lds[k8*8+j][n], h[j], l[j]);
    h0.x=h[0];h0.y=h[1];h0.z=h[2];h0.w=h[3]; h1.x=h[4];h1.y=h[5];h1.z=h[6];h1.w=h[7];
    l0.x=l[0];l0.y=l[1];l0.z=l[2];l0.w=l[3]; l1.x=l[4];l1.y=l[5];l1.z=l[6];l1.w=l[7];
    size_t dst = (size_t)(n0+n)*1536 + k0 + k8*8;
    *(ushort4*)(wt_hi+dst) = h0; *(ushort4*)(wt_hi+dst+4) = h1;
    *(ushort4*)(wt_lo+dst) = l0; *(ushort4*)(wt_lo+dst+4) = l1;
  }
}

// ---- one-time: embeddings -> hi/lo planes for all t ----
__global__ __launch_bounds__(128) void k_prep(const int* __restrict__ inp,
    const float* __restrict__ emb0, const float* __restrict__ wemb,
    unsigned short* __restrict__ eh, unsigned short* __restrict__ el){
  int n = blockIdx.x; int t = n >> 6, b = n & 63;
  const float* src = (t==0) ? emb0 + (size_t)b*HH
                            : wemb + (size_t)inp[b*TT + (t-1)]*HH;
  float4 v = ((const float4*)src)[threadIdx.x];
  ushort4 h, l;
  split2(v.x,h.x,l.x); split2(v.y,h.y,l.y); split2(v.z,h.z,l.z); split2(v.w,h.w,l.w);
  size_t base = ((size_t)t*BB + b)*HH + threadIdx.x*4;
  *(ushort4*)(eh+base) = h; *(ushort4*)(el+base) = l;
}

// ---- one-time: state init ----
__global__ __launch_bounds__(256) void k_init(const float* __restrict__ th0,
    const float* __restrict__ tc0, const float* __restrict__ xh0,
    const float* __restrict__ xc0, const float* __restrict__ out0,
    float* __restrict__ ws){
  unsigned short* hhp = (unsigned short*)(ws + OFF_HHP);
  unsigned short* hlp = (unsigned short*)(ws + OFF_HLP);
  unsigned short* oh  = (unsigned short*)(ws + OFF_OH);
  unsigned short* ol  = (unsigned short*)(ws + OFF_OL);
  int which = blockIdx.x >> 5;
  int idx = (blockIdx.x & 31)*256 + threadIdx.x;   // f4 idx 0..8191
  if (which==0){ ((float4*)(ws+OFF_TC))[idx] = ((const float4*)tc0)[idx]; return; }
  if (which==1){ ((float4*)(ws+OFF_XC))[idx] = ((const float4*)xc0)[idx]; return; }
  const float* s = which==2? th0 : which==3? xh0 : out0;
  float4 v = ((const float4*)s)[idx];
  ushort4 h, l;
  split2(v.x,h.x,l.x); split2(v.y,h.y,l.y); split2(v.z,h.z,l.z); split2(v.w,h.w,l.w);
  if (which==4){
    *(ushort4*)(oh + (size_t)idx*4) = h; *(ushort4*)(ol + (size_t)idx*4) = l;
  } else {
    size_t base = (size_t)(which-2)*BB*HH + (size_t)idx*4;
    *(ushort4*)(hhp+base) = h; *(ushort4*)(hlp+base) = l;
  }
}

// ---- per step: MFMA gate GEMM. grid 256 = bn(32) x ks(8), 256 thr ----
// A (virtual 128x1536) = [E|O|TH ; E|O|XH] hi/lo planes; W = WT hi/lo.
// G_part[ks][128][2048] fp32.
__global__ __launch_bounds__(256) void k_gemm(const unsigned short* __restrict__ wt_hi,
    const unsigned short* __restrict__ wt_lo, const unsigned short* __restrict__ eh,
    const unsigned short* __restrict__ el, const unsigned short* __restrict__ oh,
    const unsigned short* __restrict__ ol, const unsigned short* __restrict__ hhp,
    const unsigned short* __restrict__ hlp, float* __restrict__ gpart, int t){
  int tid = threadIdx.x, lane = tid & 63, wave = tid >> 6;
  int bn = blockIdx.x & 31, ks = blockIdx.x >> 5;
  int lm = lane & 15, lk = (lane >> 4) << 3;
  f32x4 acc[2][4];
  #pragma unroll
  for (int i=0;i<2;i++)
    #pragma unroll
    for (int j=0;j<4;j++) acc[i][j] = (f32x4){0.f,0.f,0.f,0.f};
  size_t ebase[2], obase[2], hbase[2];
  #pragma unroll
  for (int i=0;i<2;i++){
    int r = (wave*2 + i)*16 + lm;
    int b = r & 63, br = r >> 6;
    ebase[i] = ((size_t)t*BB + b)*HH;
    obase[i] = (size_t)b*HH;
    hbase[i] = ((size_t)br*BB + b)*HH;
  }
  size_t wb[4];
  #pragma unroll
  for (int j=0;j<4;j++) wb[j] = (size_t)(bn*64 + j*16 + lm)*1536;
  #pragma unroll
  for (int c=0;c<6;c++){
    int kc = ks*192 + c*32;
    int sec = kc >> 9;
    int kk = (kc & 511) + lk;
    const unsigned short* ph = sec==0? eh : sec==1? oh : hhp;
    const unsigned short* pl = sec==0? el : sec==1? ol : hlp;
    bf16x8 ah[2], al[2], wh_[4], wl_[4];
    #pragma unroll
    for (int i=0;i<2;i++){
      size_t off = (sec==0? ebase[i] : sec==1? obase[i] : hbase[i]) + kk;
      ah[i] = *(const bf16x8*)(ph + off);
      al[i] = *(const bf16x8*)(pl + off);
    }
    int kw = kc + lk;
    #pragma unroll
    for (int j=0;j<4;j++){
      wh_[j] = *(const bf16x8*)(wt_hi + wb[j] + kw);
      wl_[j] = *(const bf16x8*)(wt_lo + wb[j] + kw);
    }
    #pragma unroll
    for (int i=0;i<2;i++)
      #pragma unroll
      for (int j=0;j<4;j++){
        acc[i][j] = __builtin_amdgcn_mfma_f32_16x16x32_bf16(ah[i], wh_[j], acc[i][j], 0,0,0);
        acc[i][j] = __builtin_amdgcn_mfma_f32_16x16x32_bf16(ah[i], wl_[j], acc[i][j], 0,0,0);
        acc[i][j] = __builtin_amdgcn_mfma_f32_16x16x32_bf16(al[i], wh_[j], acc[i][j], 0,0,0);
      }
  }
  int lr4 = (lane >> 4) * 4;
  #pragma unroll
  for (int i=0;i<2;i++){
    int m0 = (wave*2+i)*16;
    #pragma unroll
    for (int j=0;j<4;j++){
      int col = bn*64 + j*16 + lm;
      #pragma unroll
      for (int q=0;q<4;q++){
        int row = m0 + lr4 + q;
        gpart[((size_t)ks*128 + row)*H4 + col] = acc[i][j][q];
      }
    }
  }
}

// ---- per step: 8-way partial reduce + LSTM pointwise. grid 128 x 256 ----
__global__ __launch_bounds__(256) void k_lstm(float* __restrict__ ws,
    const float* __restrict__ bias, int rs){
  int gid = blockIdx.x*256 + threadIdx.x;   // 0..32767
  int b = gid >> 9, j = gid & 511;
  int wsl = rs ^ 1;
  const float* gp = ws + OFF_G;
  unsigned short* hhp = (unsigned short*)(ws + OFF_HHP);
  unsigned short* hlp = (unsigned short*)(ws + OFF_HLP);
  #pragma unroll
  for (int br=0;br<2;br++){
    float g0=0.f,g1=0.f,g2=0.f,g3=0.f;
    #pragma unroll
    for (int ks=0;ks<8;ks++){
      size_t base = ((size_t)ks*128 + br*64 + b)*H4 + j;
      g0 += gp[base]; g1 += gp[base+512]; g2 += gp[base+1024]; g3 += gp[base+1536];
    }
    g0 += bias[j]; g1 += bias[512+j]; g2 += bias[1024+j]; g3 += bias[1536+j];
    size_t hoff = (br? OFF_XH : OFF_TH), coff = (br? OFF_XC : OFF_TC);
    float cold = ws[coff + (size_t)rs*BB*HH + (size_t)b*HH + j];
    float cn = sigm(g1)*cold + sigm(g0)*tanhf(g2);
    float hn = sigm(g3)*tanhf(cn);
    ws[coff + (size_t)wsl*BB*HH + (size_t)b*HH + j] = cn;
    ws[hoff + (size_t)wsl*BB*HH + (size_t)b*HH + j] = hn;
    unsigned short h_, l_;
    split2(hn, h_, l_);
    hhp[(size_t)(br*64+b)*HH + j] = h_;
    hlp[(size_t)(br*64+b)*HH + j] = l_;
  }
}

// ---- per step: targets = [th; xh] @ W_in. grid 256, 256 thr ----
__global__ __launch_bounds__(256) void k_tgt(const float* __restrict__ W_in,
    float* __restrict__ ws, int wsl){
  int lane = threadIdx.x & 63, wave = threadIdx.x >> 6;
  int rt = blockIdx.x >> 3, ct = blockIdx.x & 7;
  int row = rt*4 + wave;
  int branch = row >> 6, b = row & 63;
  const float* hrow = ws + (branch? OFF_XH : OFF_TH) + (size_t)wsl*BB*HH + (size_t)b*HH;
  int c = ct*64 + lane;
  float acc = 0.f;
  #pragma unroll 4
  for (int k=0;k<HH;k++) acc += hrow[k] * W_in[(size_t)k*HH + c];
  ws[OFF_TGT + (size_t)row*HH + c] = acc;
}

// ---- per step: flash attention partial. grid 256 = (sh,b,branch), 256 thr ----
__global__ __launch_bounds__(256) void k_attn(const float* __restrict__ tree_ctx,
    const float* __restrict__ text_ctx, float* __restrict__ ws){
  int blk = blockIdx.x;
  int branch = blk & 1, b = (blk>>1)&63, sh = blk>>7;
  int tid = threadIdx.x, lane = tid & 63, wave = tid >> 6;
  __shared__ float tgt_s[512];
  __shared__ float sc[2][4];
  if (tid < 128)
    ((float4*)tgt_s)[tid] = ((const float4*)(ws + OFF_TGT + (size_t)(branch*64+b)*HH))[tid];
  __syncthreads();
  const float* ctx = (branch? text_ctx : tree_ctx) + (size_t)b*SS*HH;
  int s0 = sh*200;
  float m = -INFINITY, l = 0.f, acc0 = 0.f, acc1 = 0.f;
  int h0 = tid*2;
  for (int tile=0; tile<50; tile++){
    int s = s0 + tile*4 + wave;
    const float* crow = ctx + (size_t)s*HH + lane*8;
    float4 ca = *(const float4*)crow;
    float4 cb = *(const float4*)(crow+4);
    float4 ta = *(const float4*)&tgt_s[lane*8];
    float4 tb = *(const float4*)&tgt_s[lane*8+4];
    float p = ca.x*ta.x + ca.y*ta.y + ca.z*ta.z + ca.w*ta.w
            + cb.x*tb.x + cb.y*tb.y + cb.z*tb.z + cb.w*tb.w;
    #pragma unroll
    for (int off=32; off; off>>=1) p += __shfl_xor(p, off, 64);
    if (lane==0) sc[tile&1][wave] = p;
    __syncthreads();
    float sv0 = sc[tile&1][0], sv1 = sc[tile&1][1];
    float sv2 = sc[tile&1][2], sv3 = sc[tile&1][3];
    float tm = fmaxf(fmaxf(sv0,sv1), fmaxf(sv2,sv3));
    float mn = fmaxf(m, tm);
    float scale = __expf(m - mn);
    float p0 = __expf(sv0-mn), p1 = __expf(sv1-mn);
    float p2 = __expf(sv2-mn), p3 = __expf(sv3-mn);
    m = mn;
    l = l*scale + (p0+p1+p2+p3);
    const float* c0 = ctx + (size_t)(s0 + tile*4)*HH + h0;
    float2 v0 = *(const float2*)c0;
    float2 v1 = *(const float2*)(c0 + HH);
    float2 v2 = *(const float2*)(c0 + 2*HH);
    float2 v3 = *(const float2*)(c0 + 3*HH);
    acc0 = acc0*scale + p0*v0.x + p1*v1.x + p2*v2.x + p3*v3.x;
    acc1 = acc1*scale + p0*v0.y + p1*v1.y + p2*v2.y + p3*v3.y;
  }
  int pidx = (branch*64 + b)*2 + sh;
  ws[OFF_PACC + (size_t)pidx*HH + h0]   = acc0;
  ws[OFF_PACC + (size_t)pidx*HH + h0+1] = acc1;
  if (tid==0){ ws[OFF_PML + pidx*2] = m; ws[OFF_PML + pidx*2 + 1] = l; }
}

// ---- per step: split-K GEMM for out = combined @ W_out (partials). grid 256 ----
__global__ __launch_bounds__(256) void k_outB(const float* __restrict__ W_out,
    float* __restrict__ ws, int wsl){
  __shared__ float comb_s[16][256];
  __shared__ float ce_s[16][2];
  int tid = threadIdx.x, lane = tid & 63, wave = tid >> 6;
  int blk = blockIdx.x;
  int ct = blk & 7, bg = (blk>>3)&3, ks = blk>>5;
  int b0 = bg*16;
  int k0 = ks*256;
  int sec = ks >> 1;
  int kk0 = (ks & 1)*256;
  int c = ct*64 + lane;
  if (sec < 2){
    if (tid < 16){
      int b = b0 + tid;
      int p0 = (sec*64 + b)*2;
      float m0 = ws[OFF_PML + p0*2],     l0 = ws[OFF_PML + p0*2+1];
      float m1 = ws[OFF_PML + (p0+1)*2], l1 = ws[OFF_PML + (p0+1)*2+1];
      float M = fmaxf(m0, m1);
      float e0 = __expf(m0-M), e1 = __expf(m1-M);
      float L = l0*e0 + l1*e1;
      ce_s[tid][0] = e0/L; ce_s[tid][1] = e1/L;
    }
    __syncthreads();
  }
  #pragma unroll
  for (int i=0;i<4;i++){
    int flat = tid + i*256;
    int row = flat >> 6;
    int q   = flat & 63;
    int b = b0 + row;
    int h = kk0 + q*4;
    float4 v;
    if (sec < 2){
      int p0 = (sec*64 + b)*2;
      float4 a0 = *(const float4*)(ws + OFF_PACC + (size_t)p0*HH + h);
      float4 a1 = *(const float4*)(ws + OFF_PACC + (size_t)(p0+1)*HH + h);
      float c0 = ce_s[row][0], c1 = ce_s[row][1];
      v.x = a0.x*c0 + a1.x*c1; v.y = a0.y*c0 + a1.y*c1;
      v.z = a0.z*c0 + a1.z*c1; v.w = a0.w*c0 + a1.w*c1;
    } else {
      size_t hoff = (sec==2 ? OFF_TH : OFF_XH) + (size_t)wsl*BB*HH;
      v = *(const float4*)(ws + hoff + (size_t)b*HH + h);
    }
    *(float4*)&comb_s[row][q*4] = v;
  }
  __syncthreads();
  float acc[4] = {0,0,0,0};
  #pragma unroll 4
  for (int k=0;k<256;k++){
    float wv = W_out[(size_t)(k0+k)*HH + c];
    #pragma unroll
    for (int i=0;i<4;i++) acc[i] += comb_s[wave*4+i][k]*wv;
  }
  #pragma unroll
  for (int i=0;i<4;i++){
    int b = b0 + wave*4 + i;
    ws[OFF_PART + ((size_t)ks*BB + b)*HH + c] = acc[i];
  }
}

// ---- per step: reduce 8 partials + tanh + store + O planes. grid 32 x 256 ----
__global__ __launch_bounds__(256) void k_outC(float* __restrict__ ws,
    float* __restrict__ dout, int t){
  int gid = blockIdx.x*256 + threadIdx.x;   // 0..8191 f4
  int b = gid >> 7, cq = gid & 127;
  int c0 = cq*4;
  float4 s = {0,0,0,0};
  #pragma unroll
  for (int ks=0;ks<8;ks++){
    float4 p = *(const float4*)(ws + OFF_PART + ((size_t)ks*BB + b)*HH + c0);
    s.x += p.x; s.y += p.y; s.z += p.z; s.w += p.w;
  }
  float4 o;
  o.x = tanhf(s.x); o.y = tanhf(s.y); o.z = tanhf(s.z); o.w = tanhf(s.w);
  *(float4*)(dout + ((size_t)b*TT + t)*HH + c0) = o;
  ushort4 h, l;
  split2(o.x,h.x,l.x); split2(o.y,h.y,l.y); split2(o.z,h.z,l.z); split2(o.w,h.w,l.w);
  unsigned short* oh = (unsigned short*)(ws + OFF_OH);
  unsigned short* ol = (unsigned short*)(ws + OFF_OL);
  *(ushort4*)(oh + (size_t)b*HH + c0) = h;
  *(ushort4*)(ol + (size_t)b*HH + c0) = l;
}

extern "C" void kernel_launch(void* const* d_in, const int* in_sizes, int n_in,
                              void* d_out, int out_size, void* d_ws, size_t ws_size,
                              hipStream_t stream){
  const int*   inp   = (const int*)  d_in[0];
  const float* emb0  = (const float*)d_in[1];
  const float* out0  = (const float*)d_in[2];
  const float* th0   = (const float*)d_in[3];
  const float* tc0   = (const float*)d_in[4];
  const float* trctx = (const float*)d_in[5];
  const float* xh0   = (const float*)d_in[6];
  const float* xc0   = (const float*)d_in[7];
  const float* txctx = (const float*)d_in[8];
  const float* wemb  = (const float*)d_in[9];
  const float* Wx    = (const float*)d_in[10];
  const float* Wh    = (const float*)d_in[11];
  const float* bias  = (const float*)d_in[12];
  const float* W_in  = (const float*)d_in[13];
  const float* W_out = (const float*)d_in[14];
  float* ws  = (float*)d_ws;
  float* out = (float*)d_out;
  unsigned short* wt_hi = (unsigned short*)(ws + OFF_WT_HI);
  unsigned short* wt_lo = (unsigned short*)(ws + OFF_WT_LO);
  unsigned short* eh = (unsigned short*)(ws + OFF_EH);
  unsigned short* el = (unsigned short*)(ws + OFF_EL);
  unsigned short* oh = (unsigned short*)(ws + OFF_OH);
  unsigned short* ol = (unsigned short*)(ws + OFF_OL);
  unsigned short* hhp = (unsigned short*)(ws + OFF_HHP);
  unsigned short* hlp = (unsigned short*)(ws + OFF_HLP);
  float* gpart = ws + OFF_G;

  hipLaunchKernelGGL(k_wprep, dim3(768),   dim3(256), 0, stream, Wx, Wh, wt_hi, wt_lo);
  hipLaunchKernelGGL(k_prep,  dim3(TT*BB), dim3(128), 0, stream, inp, emb0, wemb, eh, el);
  hipLaunchKernelGGL(k_init,  dim3(160),   dim3(256), 0, stream, th0, tc0, xh0, xc0, out0, ws);
  for (int t=0; t<TT; t++){
    int rs = t & 1, wsl = rs ^ 1;
    hipLaunchKernelGGL(k_gemm, dim3(256), dim3(256), 0, stream,
                       wt_hi, wt_lo, eh, el, oh, ol, hhp, hlp, gpart, t);
    hipLaunchKernelGGL(k_lstm, dim3(128), dim3(256), 0, stream, ws, bias, rs);
    hipLaunchKernelGGL(k_tgt,  dim3(256), dim3(256), 0, stream, W_in, ws, wsl);
    hipLaunchKernelGGL(k_attn, dim3(256), dim3(256), 0, stream, trctx, txctx, ws);
    hipLaunchKernelGGL(k_outB, dim3(256), dim3(256), 0, stream, W_out, ws, wsl);
    hipLaunchKernelGGL(k_outC, dim3(32),  dim3(256), 0, stream, ws, out, t);
  }
}

// Round 4
// 3357.700 us; speedup vs baseline: 2.9945x; 1.0397x over previous
//
#include <hip/hip_runtime.h>
#include <hip/hip_bf16.h>
#include <math.h>

#define BB 64
#define TT 32
#define HH 512
#define H2 1024
#define H4 2048
#define SS 400

// ---- workspace layout (float offsets) ----
#define OFF_WT_HI 0u          // WT hi plane: [2048 n][1536 k] bf16 = 1572864 floats
#define OFF_WT_LO 1572864u
#define OFF_EH    3145728u    // E hi: [32][64][512] bf16 = 524288 floats
#define OFF_EL    3670016u
#define OFF_OH    4194304u    // O planes [64][512] bf16
#define OFF_OL    4210688u
#define OFF_HHP   4227072u    // h planes [2br][64][512] bf16
#define OFF_HLP   4259840u
#define OFF_TC    4292608u    // fp32 [2 slot][64][512]
#define OFF_XC    4358144u
#define OFF_TH    4423680u    // fp32 [2 slot][64][512]
#define OFF_XH    4489216u
#define OFF_G     4554752u    // [8ks][128][2048] fp32 = 2097152
#define OFF_TGT   6651904u    // [2][64][512]
#define OFF_PACC  6717440u    // [1024 pidx][512] = 524288
#define OFF_PML   7241728u    // [1024][2] (m,l)
#define OFF_PART  OFF_G       // k_out partials alias consumed G

typedef short bf16x8 __attribute__((ext_vector_type(8)));
typedef float f32x4  __attribute__((ext_vector_type(4)));

__device__ __forceinline__ float sigm(float x){ return 1.f/(1.f+__expf(-x)); }

__device__ __forceinline__ unsigned short bf_rn(float x){
  unsigned int u = __float_as_uint(x);
  return (unsigned short)((u + 0x7fffu + ((u>>16)&1u)) >> 16);
}
__device__ __forceinline__ void split2(float x, unsigned short &h, unsigned short &l){
  h = bf_rn(x);
  float hf = __uint_as_float(((unsigned int)h)<<16);
  l = bf_rn(x - hf);
}

// ---- one-time: transpose W=[Wx;Wh] (1536x2048) -> WT[n][k] hi/lo bf16 ----
__global__ __launch_bounds__(256) void k_wprep(const float* __restrict__ Wx,
    const float* __restrict__ Wh, unsigned short* __restrict__ wt_hi,
    unsigned short* __restrict__ wt_lo){
  __shared__ float lds[64][68];
  int bk = blockIdx.x >> 5, bn = blockIdx.x & 31;
  int k0 = bk*64, n0 = bn*64;
  int tid = threadIdx.x;
  #pragma unroll
  for (int i=0;i<4;i++){
    int flat = tid + i*256;          // 0..1023 f4
    int k = flat >> 4, nq = flat & 15;
    int kg = k0 + k;
    const float* srow = (kg < 1024) ? Wx + (size_t)kg*H4 : Wh + (size_t)(kg-1024)*H4;
    float4 v = *(const float4*)(srow + n0 + nq*4);
    *(float4*)&lds[k][nq*4] = v;
  }
  __syncthreads();
  #pragma unroll
  for (int i=0;i<2;i++){
    int flat = tid + i*256;          // 0..511
    int n = flat >> 3, k8 = flat & 7;
    ushort4 h0, h1, l0, l1;
    unsigned short h[8], l[8];
    #pragma unroll
    for (int j=0;j<8;j++) split2(lds[k8*8+j][n], h[j], l[j]);
    h0.x=h[0];h0.y=h[1];h0.z=h[2];h0.w=h[3]; h1.x=h[4];h1.y=h[5];h1.z=h[6];h1.w=h[7];
    l0.x=l[0];l0.y=l[1];l0.z=l[2];l0.w=l[3]; l1.x=l[4];l1.y=l[5];l1.z=l[6];l1.w=l[7];
    size_t dst = (size_t)(n0+n)*1536 + k0 + k8*8;
    *(ushort4*)(wt_hi+dst) = h0; *(ushort4*)(wt_hi+dst+4) = h1;
    *(ushort4*)(wt_lo+dst) = l0; *(ushort4*)(wt_lo+dst+4) = l1;
  }
}

// ---- one-time: embeddings -> hi/lo planes for all t ----
__global__ __launch_bounds__(128) void k_prep(const int* __restrict__ inp,
    const float* __restrict__ emb0, const float* __restrict__ wemb,
    unsigned short* __restrict__ eh, unsigned short* __restrict__ el){
  int n = blockIdx.x; int t = n >> 6, b = n & 63;
  const float* src = (t==0) ? emb0 + (size_t)b*HH
                            : wemb + (size_t)inp[b*TT + (t-1)]*HH;
  float4 v = ((const float4*)src)[threadIdx.x];
  ushort4 h, l;
  split2(v.x,h.x,l.x); split2(v.y,h.y,l.y); split2(v.z,h.z,l.z); split2(v.w,h.w,l.w);
  size_t base = ((size_t)t*BB + b)*HH + threadIdx.x*4;
  *(ushort4*)(eh+base) = h; *(ushort4*)(el+base) = l;
}

// ---- one-time: state init ----
__global__ __launch_bounds__(256) void k_init(const float* __restrict__ th0,
    const float* __restrict__ tc0, const float* __restrict__ xh0,
    const float* __restrict__ xc0, const float* __restrict__ out0,
    float* __restrict__ ws){
  unsigned short* hhp = (unsigned short*)(ws + OFF_HHP);
  unsigned short* hlp = (unsigned short*)(ws + OFF_HLP);
  unsigned short* oh  = (unsigned short*)(ws + OFF_OH);
  unsigned short* ol  = (unsigned short*)(ws + OFF_OL);
  int which = blockIdx.x >> 5;
  int idx = (blockIdx.x & 31)*256 + threadIdx.x;   // f4 idx 0..8191
  if (which==0){ ((float4*)(ws+OFF_TC))[idx] = ((const float4*)tc0)[idx]; return; }
  if (which==1){ ((float4*)(ws+OFF_XC))[idx] = ((const float4*)xc0)[idx]; return; }
  const float* s = which==2? th0 : which==3? xh0 : out0;
  float4 v = ((const float4*)s)[idx];
  ushort4 h, l;
  split2(v.x,h.x,l.x); split2(v.y,h.y,l.y); split2(v.z,h.z,l.z); split2(v.w,h.w,l.w);
  if (which==4){
    *(ushort4*)(oh + (size_t)idx*4) = h; *(ushort4*)(ol + (size_t)idx*4) = l;
  } else {
    size_t base = (size_t)(which-2)*BB*HH + (size_t)idx*4;
    *(ushort4*)(hhp+base) = h; *(ushort4*)(hlp+base) = l;
  }
}

// ---- per step: MFMA gate GEMM. grid 256 = bn(32) x ks(8), 256 thr ----
__global__ __launch_bounds__(256) void k_gemm(const unsigned short* __restrict__ wt_hi,
    const unsigned short* __restrict__ wt_lo, const unsigned short* __restrict__ eh,
    const unsigned short* __restrict__ el, const unsigned short* __restrict__ oh,
    const unsigned short* __restrict__ ol, const unsigned short* __restrict__ hhp,
    const unsigned short* __restrict__ hlp, float* __restrict__ gpart, int t){
  int tid = threadIdx.x, lane = tid & 63, wave = tid >> 6;
  int bn = blockIdx.x & 31, ks = blockIdx.x >> 5;
  int lm = lane & 15, lk = (lane >> 4) << 3;
  f32x4 acc[2][4];
  #pragma unroll
  for (int i=0;i<2;i++)
    #pragma unroll
    for (int j=0;j<4;j++) acc[i][j] = (f32x4){0.f,0.f,0.f,0.f};
  size_t ebase[2], obase[2], hbase[2];
  #pragma unroll
  for (int i=0;i<2;i++){
    int r = (wave*2 + i)*16 + lm;
    int b = r & 63, br = r >> 6;
    ebase[i] = ((size_t)t*BB + b)*HH;
    obase[i] = (size_t)b*HH;
    hbase[i] = ((size_t)br*BB + b)*HH;
  }
  size_t wb[4];
  #pragma unroll
  for (int j=0;j<4;j++) wb[j] = (size_t)(bn*64 + j*16 + lm)*1536;
  #pragma unroll
  for (int c=0;c<6;c++){
    int kc = ks*192 + c*32;
    int sec = kc >> 9;
    int kk = (kc & 511) + lk;
    const unsigned short* ph = sec==0? eh : sec==1? oh : hhp;
    const unsigned short* pl = sec==0? el : sec==1? ol : hlp;
    bf16x8 ah[2], al[2], wh_[4], wl_[4];
    #pragma unroll
    for (int i=0;i<2;i++){
      size_t off = (sec==0? ebase[i] : sec==1? obase[i] : hbase[i]) + kk;
      ah[i] = *(const bf16x8*)(ph + off);
      al[i] = *(const bf16x8*)(pl + off);
    }
    int kw = kc + lk;
    #pragma unroll
    for (int j=0;j<4;j++){
      wh_[j] = *(const bf16x8*)(wt_hi + wb[j] + kw);
      wl_[j] = *(const bf16x8*)(wt_lo + wb[j] + kw);
    }
    #pragma unroll
    for (int i=0;i<2;i++)
      #pragma unroll
      for (int j=0;j<4;j++){
        acc[i][j] = __builtin_amdgcn_mfma_f32_16x16x32_bf16(ah[i], wh_[j], acc[i][j], 0,0,0);
        acc[i][j] = __builtin_amdgcn_mfma_f32_16x16x32_bf16(ah[i], wl_[j], acc[i][j], 0,0,0);
        acc[i][j] = __builtin_amdgcn_mfma_f32_16x16x32_bf16(al[i], wh_[j], acc[i][j], 0,0,0);
      }
  }
  int lr4 = (lane >> 4) * 4;
  #pragma unroll
  for (int i=0;i<2;i++){
    int m0 = (wave*2+i)*16;
    #pragma unroll
    for (int j=0;j<4;j++){
      int col = bn*64 + j*16 + lm;
      #pragma unroll
      for (int q=0;q<4;q++){
        int row = m0 + lr4 + q;
        gpart[((size_t)ks*128 + row)*H4 + col] = acc[i][j][q];
      }
    }
  }
}

// ---- per step: 8-way partial reduce + LSTM pointwise. grid 128 x 256 ----
__global__ __launch_bounds__(256) void k_lstm(float* __restrict__ ws,
    const float* __restrict__ bias, int rs){
  int gid = blockIdx.x*256 + threadIdx.x;   // 0..32767
  int b = gid >> 9, j = gid & 511;
  int wsl = rs ^ 1;
  const float* gp = ws + OFF_G;
  unsigned short* hhp = (unsigned short*)(ws + OFF_HHP);
  unsigned short* hlp = (unsigned short*)(ws + OFF_HLP);
  #pragma unroll
  for (int br=0;br<2;br++){
    float g0=0.f,g1=0.f,g2=0.f,g3=0.f;
    #pragma unroll
    for (int ks=0;ks<8;ks++){
      size_t base = ((size_t)ks*128 + br*64 + b)*H4 + j;
      g0 += gp[base]; g1 += gp[base+512]; g2 += gp[base+1024]; g3 += gp[base+1536];
    }
    g0 += bias[j]; g1 += bias[512+j]; g2 += bias[1024+j]; g3 += bias[1536+j];
    size_t hoff = (br? OFF_XH : OFF_TH), coff = (br? OFF_XC : OFF_TC);
    float cold = ws[coff + (size_t)rs*BB*HH + (size_t)b*HH + j];
    float cn = sigm(g1)*cold + sigm(g0)*tanhf(g2);
    float hn = sigm(g3)*tanhf(cn);
    ws[coff + (size_t)wsl*BB*HH + (size_t)b*HH + j] = cn;
    ws[hoff + (size_t)wsl*BB*HH + (size_t)b*HH + j] = hn;
    unsigned short h_, l_;
    split2(hn, h_, l_);
    hhp[(size_t)(br*64+b)*HH + j] = h_;
    hlp[(size_t)(br*64+b)*HH + j] = l_;
  }
}

// ---- per step: targets = [th; xh] @ W_in. grid 256, 256 thr ----
__global__ __launch_bounds__(256) void k_tgt(const float* __restrict__ W_in,
    float* __restrict__ ws, int wsl){
  int lane = threadIdx.x & 63, wave = threadIdx.x >> 6;
  int rt = blockIdx.x >> 3, ct = blockIdx.x & 7;
  int row = rt*4 + wave;
  int branch = row >> 6, b = row & 63;
  const float* hrow = ws + (branch? OFF_XH : OFF_TH) + (size_t)wsl*BB*HH + (size_t)b*HH;
  int c = ct*64 + lane;
  float acc = 0.f;
  #pragma unroll 4
  for (int k=0;k<HH;k++) acc += hrow[k] * W_in[(size_t)k*HH + c];
  ws[OFF_TGT + (size_t)row*HH + c] = acc;
}

// ---- per step: two-pass flash attention partial.
// grid 1024 = sh(8) x b(64) x branch(2), 256 thr. Each block: 50 s-rows.
__global__ __launch_bounds__(256) void k_attn(const float* __restrict__ tree_ctx,
    const float* __restrict__ text_ctx, float* __restrict__ ws){
  int blk = blockIdx.x;
  int branch = blk & 1, b = (blk>>1)&63, sh = blk>>7;   // sh 0..7
  int tid = threadIdx.x, lane = tid & 63, wave = tid >> 6;
  __shared__ float tgt_s[512];
  __shared__ float sc_s[64];
  __shared__ float w_s[64];
  if (tid < 128)
    ((float4*)tgt_s)[tid] = ((const float4*)(ws + OFF_TGT + (size_t)(branch*64+b)*HH))[tid];
  if (tid >= 128 && tid < 192) sc_s[tid-128] = -INFINITY;
  __syncthreads();
  const float* ctx = (branch? text_ctx : tree_ctx) + ((size_t)b*SS + sh*50)*HH;
  // pass 1: scores (one coalesced row per wave-iteration, no barriers)
  float4 ta = *(const float4*)&tgt_s[lane*8];
  float4 tb = *(const float4*)&tgt_s[lane*8+4];
  for (int r = wave; r < 50; r += 4){
    const float* crow = ctx + (size_t)r*HH + lane*8;
    float4 ca = *(const float4*)crow;
    float4 cb = *(const float4*)(crow+4);
    float p = ca.x*ta.x + ca.y*ta.y + ca.z*ta.z + ca.w*ta.w
            + cb.x*tb.x + cb.y*tb.y + cb.z*tb.z + cb.w*tb.w;
    #pragma unroll
    for (int off=32; off; off>>=1) p += __shfl_xor(p, off, 64);
    if (lane==0) sc_s[r] = p;
  }
  __syncthreads();
  // wave 0: softmax partial (m, l) over 50, unnormalized weights -> LDS
  if (wave==0){
    float s = sc_s[lane];
    float m = s;
    #pragma unroll
    for (int off=32; off; off>>=1) m = fmaxf(m, __shfl_xor(m, off, 64));
    float e = (lane<50)? __expf(s-m) : 0.f;
    w_s[lane] = e;
    float l = e;
    #pragma unroll
    for (int off=32; off; off>>=1) l += __shfl_xor(l, off, 64);
    if (lane==0){
      int pidx = (branch*64 + b)*8 + sh;
      ws[OFF_PML + (size_t)pidx*2]   = m;
      ws[OFF_PML + (size_t)pidx*2+1] = l;
    }
  }
  __syncthreads();
  // pass 2: weighted sum, thread owns 2 columns; 50 independent FMAs
  int c0 = tid*2;
  float a0 = 0.f, a1 = 0.f;
  #pragma unroll 10
  for (int s=0;s<50;s++){
    float w = w_s[s];
    float2 v = *(const float2*)(ctx + (size_t)s*HH + c0);
    a0 += w*v.x; a1 += w*v.y;
  }
  int pidx = (branch*64 + b)*8 + sh;
  float2 o; o.x = a0; o.y = a1;
  *(float2*)(ws + OFF_PACC + (size_t)pidx*HH + c0) = o;
}

// ---- per step: split-K GEMM for out = combined @ W_out (partials). grid 256 ----
__global__ __launch_bounds__(256) void k_outB(const float* __restrict__ W_out,
    float* __restrict__ ws, int wsl){
  __shared__ float comb_s[16][256];
  __shared__ float ce_s[16][8];
  int tid = threadIdx.x, lane = tid & 63, wave = tid >> 6;
  int blk = blockIdx.x;
  int ct = blk & 7, bg = (blk>>3)&3, ks = blk>>5;
  int b0 = bg*16;
  int k0 = ks*256;
  int sec = ks >> 1;
  int kk0 = (ks & 1)*256;
  int c = ct*64 + lane;
  if (sec < 2){
    if (tid < 16){
      int b = b0 + tid;
      int p0 = (sec*64 + b)*8;
      float mv[8], lv[8];
      float M = -INFINITY;
      #pragma unroll
      for (int i=0;i<8;i++){
        mv[i] = ws[OFF_PML + (size_t)(p0+i)*2];
        lv[i] = ws[OFF_PML + (size_t)(p0+i)*2+1];
        M = fmaxf(M, mv[i]);
      }
      float L = 0.f, ev[8];
      #pragma unroll
      for (int i=0;i<8;i++){ ev[i] = __expf(mv[i]-M); L += lv[i]*ev[i]; }
      #pragma unroll
      for (int i=0;i<8;i++) ce_s[tid][i] = ev[i]/L;
    }
    __syncthreads();
  }
  #pragma unroll
  for (int i=0;i<4;i++){
    int flat = tid + i*256;
    int row = flat >> 6;
    int q   = flat & 63;
    int b = b0 + row;
    int h = kk0 + q*4;
    float4 v;
    if (sec < 2){
      int p0 = (sec*64 + b)*8;
      v.x = 0.f; v.y = 0.f; v.z = 0.f; v.w = 0.f;
      #pragma unroll
      for (int p=0;p<8;p++){
        float4 a = *(const float4*)(ws + OFF_PACC + (size_t)(p0+p)*HH + h);
        float cw = ce_s[row][p];
        v.x += a.x*cw; v.y += a.y*cw; v.z += a.z*cw; v.w += a.w*cw;
      }
    } else {
      size_t hoff = (sec==2 ? OFF_TH : OFF_XH) + (size_t)wsl*BB*HH;
      v = *(const float4*)(ws + hoff + (size_t)b*HH + h);
    }
    *(float4*)&comb_s[row][q*4] = v;
  }
  __syncthreads();
  float acc[4] = {0,0,0,0};
  #pragma unroll 4
  for (int k=0;k<256;k++){
    float wv = W_out[(size_t)(k0+k)*HH + c];
    #pragma unroll
    for (int i=0;i<4;i++) acc[i] += comb_s[wave*4+i][k]*wv;
  }
  #pragma unroll
  for (int i=0;i<4;i++){
    int b = b0 + wave*4 + i;
    ws[OFF_PART + ((size_t)ks*BB + b)*HH + c] = acc[i];
  }
}

// ---- per step: reduce 8 partials + tanh + store + O planes. grid 32 x 256 ----
__global__ __launch_bounds__(256) void k_outC(float* __restrict__ ws,
    float* __restrict__ dout, int t){
  int gid = blockIdx.x*256 + threadIdx.x;   // 0..8191 f4
  int b = gid >> 7, cq = gid & 127;
  int c0 = cq*4;
  float4 s = {0,0,0,0};
  #pragma unroll
  for (int ks=0;ks<8;ks++){
    float4 p = *(const float4*)(ws + OFF_PART + ((size_t)ks*BB + b)*HH + c0);
    s.x += p.x; s.y += p.y; s.z += p.z; s.w += p.w;
  }
  float4 o;
  o.x = tanhf(s.x); o.y = tanhf(s.y); o.z = tanhf(s.z); o.w = tanhf(s.w);
  *(float4*)(dout + ((size_t)b*TT + t)*HH + c0) = o;
  ushort4 h, l;
  split2(o.x,h.x,l.x); split2(o.y,h.y,l.y); split2(o.z,h.z,l.z); split2(o.w,h.w,l.w);
  unsigned short* oh = (unsigned short*)(ws + OFF_OH);
  unsigned short* ol = (unsigned short*)(ws + OFF_OL);
  *(ushort4*)(oh + (size_t)b*HH + c0) = h;
  *(ushort4*)(ol + (size_t)b*HH + c0) = l;
}

extern "C" void kernel_launch(void* const* d_in, const int* in_sizes, int n_in,
                              void* d_out, int out_size, void* d_ws, size_t ws_size,
                              hipStream_t stream){
  const int*   inp   = (const int*)  d_in[0];
  const float* emb0  = (const float*)d_in[1];
  const float* out0  = (const float*)d_in[2];
  const float* th0   = (const float*)d_in[3];
  const float* tc0   = (const float*)d_in[4];
  const float* trctx = (const float*)d_in[5];
  const float* xh0   = (const float*)d_in[6];
  const float* xc0   = (const float*)d_in[7];
  const float* txctx = (const float*)d_in[8];
  const float* wemb  = (const float*)d_in[9];
  const float* Wx    = (const float*)d_in[10];
  const float* Wh    = (const float*)d_in[11];
  const float* bias  = (const float*)d_in[12];
  const float* W_in  = (const float*)d_in[13];
  const float* W_out = (const float*)d_in[14];
  float* ws  = (float*)d_ws;
  float* out = (float*)d_out;
  unsigned short* wt_hi = (unsigned short*)(ws + OFF_WT_HI);
  unsigned short* wt_lo = (unsigned short*)(ws + OFF_WT_LO);
  unsigned short* eh = (unsigned short*)(ws + OFF_EH);
  unsigned short* el = (unsigned short*)(ws + OFF_EL);
  unsigned short* oh = (unsigned short*)(ws + OFF_OH);
  unsigned short* ol = (unsigned short*)(ws + OFF_OL);
  unsigned short* hhp = (unsigned short*)(ws + OFF_HHP);
  unsigned short* hlp = (unsigned short*)(ws + OFF_HLP);
  float* gpart = ws + OFF_G;

  hipLaunchKernelGGL(k_wprep, dim3(768),   dim3(256), 0, stream, Wx, Wh, wt_hi, wt_lo);
  hipLaunchKernelGGL(k_prep,  dim3(TT*BB), dim3(128), 0, stream, inp, emb0, wemb, eh, el);
  hipLaunchKernelGGL(k_init,  dim3(160),   dim3(256), 0, stream, th0, tc0, xh0, xc0, out0, ws);
  for (int t=0; t<TT; t++){
    int rs = t & 1, wsl = rs ^ 1;
    hipLaunchKernelGGL(k_gemm, dim3(256),  dim3(256), 0, stream,
                       wt_hi, wt_lo, eh, el, oh, ol, hhp, hlp, gpart, t);
    hipLaunchKernelGGL(k_lstm, dim3(128),  dim3(256), 0, stream, ws, bias, rs);
    hipLaunchKernelGGL(k_tgt,  dim3(256),  dim3(256), 0, stream, W_in, ws, wsl);
    hipLaunchKernelGGL(k_attn, dim3(1024), dim3(256), 0, stream, trctx, txctx, ws);
    hipLaunchKernelGGL(k_outB, dim3(256),  dim3(256), 0, stream, W_out, ws, wsl);
    hipLaunchKernelGGL(k_outC, dim3(32),   dim3(256), 0, stream, ws, out, t);
  }
}

// Round 5
// 2009.429 us; speedup vs baseline: 5.0037x; 1.6710x over previous
//
#include <hip/hip_runtime.h>
#include <hip/hip_bf16.h>
#include <math.h>

#define BB 64
#define TT 32
#define HH 512
#define H2 1024
#define H4 2048
#define SS 400

// ---- workspace layout (float offsets) ----
#define OFF_WT_HI 0u          // WT hi: [2048 n][1536 k] bf16 = 1572864 floats
#define OFF_WT_LO 1572864u
#define OFF_WIT_HI 3145728u   // W_inT hi: [512 n][512 k] bf16 = 131072 floats
#define OFF_WIT_LO 3276800u
#define OFF_EH    3407872u    // E hi: [32][64][512] bf16
#define OFF_EL    3932160u
#define OFF_OH    4456448u    // O planes [64][512] bf16
#define OFF_OL    4472832u
#define OFF_HHP   4489216u    // h planes [2br*64][512] bf16
#define OFF_HLP   4521984u
#define OFF_TC    4554752u    // fp32 [2 slot][64][512]
#define OFF_XC    4620288u
#define OFF_TH    4685824u
#define OFF_XH    4751360u
#define OFF_G     4816896u    // [8ks][128][2048] fp32 = 2097152
#define OFF_TGTP  6914048u    // tgt partials [8ks][128][512] = 524288
#define OFF_PACC  7438336u    // [1024 pidx][512]
#define OFF_PML   7962624u    // [1024][2]
#define OFF_CTX16 7964672u    // bf16 ctx [2][64][400][512] = 13107200 float-slots
#define WS_NEED_F 21071872u
#define OFF_PART  OFF_G       // k_out partials alias consumed G

typedef short bf16x8 __attribute__((ext_vector_type(8)));
typedef float f32x4  __attribute__((ext_vector_type(4)));

__device__ __forceinline__ float sigm(float x){ return 1.f/(1.f+__expf(-x)); }

__device__ __forceinline__ unsigned short bf_rn(float x){
  unsigned int u = __float_as_uint(x);
  return (unsigned short)((u + 0x7fffu + ((u>>16)&1u)) >> 16);
}
__device__ __forceinline__ void split2(float x, unsigned short &h, unsigned short &l){
  h = bf_rn(x);
  float hf = __uint_as_float(((unsigned int)h)<<16);
  l = bf_rn(x - hf);
}
__device__ __forceinline__ float blo(unsigned int u){ return __uint_as_float(u<<16); }
__device__ __forceinline__ float bhi(unsigned int u){ return __uint_as_float(u & 0xffff0000u); }

// ---- one-time: transpose W=[Wx;Wh] (1536x2048) -> WT[n][k] hi/lo bf16 ----
__global__ __launch_bounds__(256) void k_wprep(const float* __restrict__ Wx,
    const float* __restrict__ Wh, unsigned short* __restrict__ wt_hi,
    unsigned short* __restrict__ wt_lo){
  __shared__ float lds[64][68];
  int bk = blockIdx.x >> 5, bn = blockIdx.x & 31;
  int k0 = bk*64, n0 = bn*64;
  int tid = threadIdx.x;
  #pragma unroll
  for (int i=0;i<4;i++){
    int flat = tid + i*256;
    int k = flat >> 4, nq = flat & 15;
    int kg = k0 + k;
    const float* srow = (kg < 1024) ? Wx + (size_t)kg*H4 : Wh + (size_t)(kg-1024)*H4;
    float4 v = *(const float4*)(srow + n0 + nq*4);
    *(float4*)&lds[k][nq*4] = v;
  }
  __syncthreads();
  #pragma unroll
  for (int i=0;i<2;i++){
    int flat = tid + i*256;
    int n = flat >> 3, k8 = flat & 7;
    ushort4 h0, h1, l0, l1;
    unsigned short h[8], l[8];
    #pragma unroll
    for (int j=0;j<8;j++) split2(lds[k8*8+j][n], h[j], l[j]);
    h0.x=h[0];h0.y=h[1];h0.z=h[2];h0.w=h[3]; h1.x=h[4];h1.y=h[5];h1.z=h[6];h1.w=h[7];
    l0.x=l[0];l0.y=l[1];l0.z=l[2];l0.w=l[3]; l1.x=l[4];l1.y=l[5];l1.z=l[6];l1.w=l[7];
    size_t dst = (size_t)(n0+n)*1536 + k0 + k8*8;
    *(ushort4*)(wt_hi+dst) = h0; *(ushort4*)(wt_hi+dst+4) = h1;
    *(ushort4*)(wt_lo+dst) = l0; *(ushort4*)(wt_lo+dst+4) = l1;
  }
}

// ---- one-time: transpose W_in (512x512) -> WIT[n][k] hi/lo bf16 ----
__global__ __launch_bounds__(256) void k_wiprep(const float* __restrict__ W_in,
    unsigned short* __restrict__ wit_hi, unsigned short* __restrict__ wit_lo){
  __shared__ float lds[64][68];
  int bk = blockIdx.x >> 3, bn = blockIdx.x & 7;
  int k0 = bk*64, n0 = bn*64;
  int tid = threadIdx.x;
  #pragma unroll
  for (int i=0;i<4;i++){
    int flat = tid + i*256;
    int k = flat >> 4, nq = flat & 15;
    float4 v = *(const float4*)(W_in + (size_t)(k0+k)*HH + n0 + nq*4);
    *(float4*)&lds[k][nq*4] = v;
  }
  __syncthreads();
  #pragma unroll
  for (int i=0;i<2;i++){
    int flat = tid + i*256;
    int n = flat >> 3, k8 = flat & 7;
    ushort4 h0, h1, l0, l1;
    unsigned short h[8], l[8];
    #pragma unroll
    for (int j=0;j<8;j++) split2(lds[k8*8+j][n], h[j], l[j]);
    h0.x=h[0];h0.y=h[1];h0.z=h[2];h0.w=h[3]; h1.x=h[4];h1.y=h[5];h1.z=h[6];h1.w=h[7];
    l0.x=l[0];l0.y=l[1];l0.z=l[2];l0.w=l[3]; l1.x=l[4];l1.y=l[5];l1.z=l[6];l1.w=l[7];
    size_t dst = (size_t)(n0+n)*HH + k0 + k8*8;
    *(ushort4*)(wit_hi+dst) = h0; *(ushort4*)(wit_hi+dst+4) = h1;
    *(ushort4*)(wit_lo+dst) = l0; *(ushort4*)(wit_lo+dst+4) = l1;
  }
}

// ---- one-time: both contexts -> bf16. grid 12800 x 256 ----
__global__ __launch_bounds__(256) void k_ctx16(const float* __restrict__ trctx,
    const float* __restrict__ txctx, unsigned short* __restrict__ ctx16){
  size_t gid = (size_t)blockIdx.x*256 + threadIdx.x;
  size_t off = gid*8;
  const size_t CH = (size_t)BB*SS*HH;
  const float* src = (off < CH) ? trctx + off : txctx + (off - CH);
  float4 a = *(const float4*)src;
  float4 c = *(const float4*)(src+4);
  ushort4 u0, u1;
  u0.x=bf_rn(a.x); u0.y=bf_rn(a.y); u0.z=bf_rn(a.z); u0.w=bf_rn(a.w);
  u1.x=bf_rn(c.x); u1.y=bf_rn(c.y); u1.z=bf_rn(c.z); u1.w=bf_rn(c.w);
  *(ushort4*)(ctx16+off) = u0;
  *(ushort4*)(ctx16+off+4) = u1;
}

// ---- one-time: embeddings -> hi/lo planes for all t ----
__global__ __launch_bounds__(128) void k_prep(const int* __restrict__ inp,
    const float* __restrict__ emb0, const float* __restrict__ wemb,
    unsigned short* __restrict__ eh, unsigned short* __restrict__ el){
  int n = blockIdx.x; int t = n >> 6, b = n & 63;
  const float* src = (t==0) ? emb0 + (size_t)b*HH
                            : wemb + (size_t)inp[b*TT + (t-1)]*HH;
  float4 v = ((const float4*)src)[threadIdx.x];
  ushort4 h, l;
  split2(v.x,h.x,l.x); split2(v.y,h.y,l.y); split2(v.z,h.z,l.z); split2(v.w,h.w,l.w);
  size_t base = ((size_t)t*BB + b)*HH + threadIdx.x*4;
  *(ushort4*)(eh+base) = h; *(ushort4*)(el+base) = l;
}

// ---- one-time: state init ----
__global__ __launch_bounds__(256) void k_init(const float* __restrict__ th0,
    const float* __restrict__ tc0, const float* __restrict__ xh0,
    const float* __restrict__ xc0, const float* __restrict__ out0,
    float* __restrict__ ws){
  unsigned short* hhp = (unsigned short*)(ws + OFF_HHP);
  unsigned short* hlp = (unsigned short*)(ws + OFF_HLP);
  unsigned short* oh  = (unsigned short*)(ws + OFF_OH);
  unsigned short* ol  = (unsigned short*)(ws + OFF_OL);
  int which = blockIdx.x >> 5;
  int idx = (blockIdx.x & 31)*256 + threadIdx.x;
  if (which==0){ ((float4*)(ws+OFF_TC))[idx] = ((const float4*)tc0)[idx]; return; }
  if (which==1){ ((float4*)(ws+OFF_XC))[idx] = ((const float4*)xc0)[idx]; return; }
  const float* s = which==2? th0 : which==3? xh0 : out0;
  float4 v = ((const float4*)s)[idx];
  ushort4 h, l;
  split2(v.x,h.x,l.x); split2(v.y,h.y,l.y); split2(v.z,h.z,l.z); split2(v.w,h.w,l.w);
  if (which==4){
    *(ushort4*)(oh + (size_t)idx*4) = h; *(ushort4*)(ol + (size_t)idx*4) = l;
  } else {
    size_t base = (size_t)(which-2)*BB*HH + (size_t)idx*4;
    *(ushort4*)(hhp+base) = h; *(ushort4*)(hlp+base) = l;
  }
}

// ---- per step: MFMA gate GEMM. grid 256 = bn(32) x ks(8), 256 thr ----
__global__ __launch_bounds__(256) void k_gemm(const unsigned short* __restrict__ wt_hi,
    const unsigned short* __restrict__ wt_lo, const unsigned short* __restrict__ eh,
    const unsigned short* __restrict__ el, const unsigned short* __restrict__ oh,
    const unsigned short* __restrict__ ol, const unsigned short* __restrict__ hhp,
    const unsigned short* __restrict__ hlp, float* __restrict__ gpart, int t){
  int tid = threadIdx.x, lane = tid & 63, wave = tid >> 6;
  int bn = blockIdx.x & 31, ks = blockIdx.x >> 5;
  int lm = lane & 15, lk = (lane >> 4) << 3;
  f32x4 acc[2][4];
  #pragma unroll
  for (int i=0;i<2;i++)
    #pragma unroll
    for (int j=0;j<4;j++) acc[i][j] = (f32x4){0.f,0.f,0.f,0.f};
  size_t ebase[2], obase[2], hbase[2];
  #pragma unroll
  for (int i=0;i<2;i++){
    int r = (wave*2 + i)*16 + lm;
    int b = r & 63, br = r >> 6;
    ebase[i] = ((size_t)t*BB + b)*HH;
    obase[i] = (size_t)b*HH;
    hbase[i] = ((size_t)br*BB + b)*HH;
  }
  size_t wb[4];
  #pragma unroll
  for (int j=0;j<4;j++) wb[j] = (size_t)(bn*64 + j*16 + lm)*1536;
  #pragma unroll
  for (int c=0;c<6;c++){
    int kc = ks*192 + c*32;
    int sec = kc >> 9;
    int kk = (kc & 511) + lk;
    const unsigned short* ph = sec==0? eh : sec==1? oh : hhp;
    const unsigned short* pl = sec==0? el : sec==1? ol : hlp;
    bf16x8 ah[2], al[2], wh_[4], wl_[4];
    #pragma unroll
    for (int i=0;i<2;i++){
      size_t off = (sec==0? ebase[i] : sec==1? obase[i] : hbase[i]) + kk;
      ah[i] = *(const bf16x8*)(ph + off);
      al[i] = *(const bf16x8*)(pl + off);
    }
    int kw = kc + lk;
    #pragma unroll
    for (int j=0;j<4;j++){
      wh_[j] = *(const bf16x8*)(wt_hi + wb[j] + kw);
      wl_[j] = *(const bf16x8*)(wt_lo + wb[j] + kw);
    }
    #pragma unroll
    for (int i=0;i<2;i++)
      #pragma unroll
      for (int j=0;j<4;j++){
        acc[i][j] = __builtin_amdgcn_mfma_f32_16x16x32_bf16(ah[i], wh_[j], acc[i][j], 0,0,0);
        acc[i][j] = __builtin_amdgcn_mfma_f32_16x16x32_bf16(ah[i], wl_[j], acc[i][j], 0,0,0);
        acc[i][j] = __builtin_amdgcn_mfma_f32_16x16x32_bf16(al[i], wh_[j], acc[i][j], 0,0,0);
      }
  }
  int lr4 = (lane >> 4) * 4;
  #pragma unroll
  for (int i=0;i<2;i++){
    int m0 = (wave*2+i)*16;
    #pragma unroll
    for (int j=0;j<4;j++){
      int col = bn*64 + j*16 + lm;
      #pragma unroll
      for (int q=0;q<4;q++){
        int row = m0 + lr4 + q;
        gpart[((size_t)ks*128 + row)*H4 + col] = acc[i][j][q];
      }
    }
  }
}

// ---- per step: 8-way partial reduce + LSTM pointwise. grid 128 x 256 ----
__global__ __launch_bounds__(256) void k_lstm(float* __restrict__ ws,
    const float* __restrict__ bias, int rs){
  int gid = blockIdx.x*256 + threadIdx.x;
  int b = gid >> 9, j = gid & 511;
  int wsl = rs ^ 1;
  const float* gp = ws + OFF_G;
  unsigned short* hhp = (unsigned short*)(ws + OFF_HHP);
  unsigned short* hlp = (unsigned short*)(ws + OFF_HLP);
  #pragma unroll
  for (int br=0;br<2;br++){
    float g0=0.f,g1=0.f,g2=0.f,g3=0.f;
    #pragma unroll
    for (int ks=0;ks<8;ks++){
      size_t base = ((size_t)ks*128 + br*64 + b)*H4 + j;
      g0 += gp[base]; g1 += gp[base+512]; g2 += gp[base+1024]; g3 += gp[base+1536];
    }
    g0 += bias[j]; g1 += bias[512+j]; g2 += bias[1024+j]; g3 += bias[1536+j];
    size_t hoff = (br? OFF_XH : OFF_TH), coff = (br? OFF_XC : OFF_TC);
    float cold = ws[coff + (size_t)rs*BB*HH + (size_t)b*HH + j];
    float cn = sigm(g1)*cold + sigm(g0)*tanhf(g2);
    float hn = sigm(g3)*tanhf(cn);
    ws[coff + (size_t)wsl*BB*HH + (size_t)b*HH + j] = cn;
    ws[hoff + (size_t)wsl*BB*HH + (size_t)b*HH + j] = hn;
    unsigned short h_, l_;
    split2(hn, h_, l_);
    hhp[(size_t)(br*64+b)*HH + j] = h_;
    hlp[(size_t)(br*64+b)*HH + j] = l_;
  }
}

// ---- per step: MFMA tgt partials = h @ W_in. grid 64 = cn(8) x ks(8) ----
__global__ __launch_bounds__(256) void k_tgtB(const unsigned short* __restrict__ wit_hi,
    const unsigned short* __restrict__ wit_lo, const unsigned short* __restrict__ hhp,
    const unsigned short* __restrict__ hlp, float* __restrict__ tgtp){
  int tid = threadIdx.x, lane = tid & 63, wave = tid >> 6;
  int cn = blockIdx.x & 7, ks = blockIdx.x >> 3;
  int lm = lane & 15, lk = (lane >> 4) << 3;
  f32x4 acc[2][4];
  #pragma unroll
  for (int i=0;i<2;i++)
    #pragma unroll
    for (int j=0;j<4;j++) acc[i][j] = (f32x4){0.f,0.f,0.f,0.f};
  size_t abase[2];
  #pragma unroll
  for (int i=0;i<2;i++) abase[i] = (size_t)(wave*32 + i*16 + lm)*HH;
  size_t wb[4];
  #pragma unroll
  for (int j=0;j<4;j++) wb[j] = (size_t)(cn*64 + j*16 + lm)*HH;
  #pragma unroll
  for (int c=0;c<2;c++){
    int kc = ks*64 + c*32;
    bf16x8 ah[2], al[2], wh_[4], wl_[4];
    #pragma unroll
    for (int i=0;i<2;i++){
      ah[i] = *(const bf16x8*)(hhp + abase[i] + kc + lk);
      al[i] = *(const bf16x8*)(hlp + abase[i] + kc + lk);
    }
    #pragma unroll
    for (int j=0;j<4;j++){
      wh_[j] = *(const bf16x8*)(wit_hi + wb[j] + kc + lk);
      wl_[j] = *(const bf16x8*)(wit_lo + wb[j] + kc + lk);
    }
    #pragma unroll
    for (int i=0;i<2;i++)
      #pragma unroll
      for (int j=0;j<4;j++){
        acc[i][j] = __builtin_amdgcn_mfma_f32_16x16x32_bf16(ah[i], wh_[j], acc[i][j], 0,0,0);
        acc[i][j] = __builtin_amdgcn_mfma_f32_16x16x32_bf16(ah[i], wl_[j], acc[i][j], 0,0,0);
        acc[i][j] = __builtin_amdgcn_mfma_f32_16x16x32_bf16(al[i], wh_[j], acc[i][j], 0,0,0);
      }
  }
  int lr4 = (lane >> 4) * 4;
  #pragma unroll
  for (int i=0;i<2;i++){
    int m0 = wave*32 + i*16;
    #pragma unroll
    for (int j=0;j<4;j++){
      int col = cn*64 + j*16 + lm;
      #pragma unroll
      for (int q=0;q<4;q++){
        int row = m0 + lr4 + q;
        tgtp[((size_t)ks*128 + row)*HH + col] = acc[i][j][q];
      }
    }
  }
}

// ---- per step: two-pass flash attention partial.
// grid 1024 = sh(8) x b(64) x branch(2), 256 thr. Each block: 50 s-rows.
__global__ __launch_bounds__(256) void k_attn(const float* __restrict__ tree_ctx,
    const float* __restrict__ text_ctx, const unsigned short* __restrict__ ctx16,
    float* __restrict__ ws, int use16){
  int blk = blockIdx.x;
  int branch = blk & 1, b = (blk>>1)&63, sh = blk>>7;
  int tid = threadIdx.x, lane = tid & 63, wave = tid >> 6;
  __shared__ float tgt_s[512];
  __shared__ float sc_s[64];
  __shared__ float w_s[64];
  int row128 = branch*64 + b;
  if (tid < 128){
    float4 s = {0,0,0,0};
    #pragma unroll
    for (int p=0;p<8;p++){
      float4 v = *(const float4*)(ws + OFF_TGTP + ((size_t)p*128 + row128)*HH + tid*4);
      s.x += v.x; s.y += v.y; s.z += v.z; s.w += v.w;
    }
    ((float4*)tgt_s)[tid] = s;
  }
  if (tid >= 128 && tid < 192) sc_s[tid-128] = -INFINITY;
  __syncthreads();
  const size_t CH = (size_t)BB*SS*HH;
  const float* ctxf = (branch? text_ctx : tree_ctx) + ((size_t)b*SS + sh*50)*HH;
  const unsigned short* c16 = ctx16 + (branch? CH:0) + ((size_t)b*SS + sh*50)*HH;
  // pass 1: scores
  float4 ta = *(const float4*)&tgt_s[lane*8];
  float4 tb = *(const float4*)&tgt_s[lane*8+4];
  if (use16){
    for (int r = wave; r < 50; r += 4){
      uint4 u = *(const uint4*)(c16 + (size_t)r*HH + lane*8);
      float p = blo(u.x)*ta.x + bhi(u.x)*ta.y + blo(u.y)*ta.z + bhi(u.y)*ta.w
              + blo(u.z)*tb.x + bhi(u.z)*tb.y + blo(u.w)*tb.z + bhi(u.w)*tb.w;
      #pragma unroll
      for (int off=32; off; off>>=1) p += __shfl_xor(p, off, 64);
      if (lane==0) sc_s[r] = p;
    }
  } else {
    for (int r = wave; r < 50; r += 4){
      const float* crow = ctxf + (size_t)r*HH + lane*8;
      float4 ca = *(const float4*)crow;
      float4 cb = *(const float4*)(crow+4);
      float p = ca.x*ta.x + ca.y*ta.y + ca.z*ta.z + ca.w*ta.w
              + cb.x*tb.x + cb.y*tb.y + cb.z*tb.z + cb.w*tb.w;
      #pragma unroll
      for (int off=32; off; off>>=1) p += __shfl_xor(p, off, 64);
      if (lane==0) sc_s[r] = p;
    }
  }
  __syncthreads();
  // wave 0: softmax partial (m, l), unnormalized weights -> LDS
  if (wave==0){
    float s = sc_s[lane];
    float m = s;
    #pragma unroll
    for (int off=32; off; off>>=1) m = fmaxf(m, __shfl_xor(m, off, 64));
    float e = (lane<50)? __expf(s-m) : 0.f;
    w_s[lane] = e;
    float l = e;
    #pragma unroll
    for (int off=32; off; off>>=1) l += __shfl_xor(l, off, 64);
    if (lane==0){
      int pidx = (branch*64 + b)*8 + sh;
      ws[OFF_PML + (size_t)pidx*2]   = m;
      ws[OFF_PML + (size_t)pidx*2+1] = l;
    }
  }
  __syncthreads();
  // pass 2: weighted sum, thread owns 2 columns
  int c0 = tid*2;
  float a0 = 0.f, a1 = 0.f;
  if (use16){
    #pragma unroll 10
    for (int s=0;s<50;s++){
      float w = w_s[s];
      unsigned int u = *(const unsigned int*)(c16 + (size_t)s*HH + c0);
      a0 += w*blo(u); a1 += w*bhi(u);
    }
  } else {
    #pragma unroll 10
    for (int s=0;s<50;s++){
      float w = w_s[s];
      float2 v = *(const float2*)(ctxf + (size_t)s*HH + c0);
      a0 += w*v.x; a1 += w*v.y;
    }
  }
  int pidx = (branch*64 + b)*8 + sh;
  float2 o; o.x = a0; o.y = a1;
  *(float2*)(ws + OFF_PACC + (size_t)pidx*HH + c0) = o;
}

// ---- per step: split-K GEMM for out = combined @ W_out (partials). grid 256 ----
__global__ __launch_bounds__(256) void k_outB(const float* __restrict__ W_out,
    float* __restrict__ ws, int wsl){
  __shared__ float comb_s[16][256];
  __shared__ float ce_s[16][8];
  int tid = threadIdx.x, lane = tid & 63, wave = tid >> 6;
  int blk = blockIdx.x;
  int ct = blk & 7, bg = (blk>>3)&3, ks = blk>>5;
  int b0 = bg*16;
  int k0 = ks*256;
  int sec = ks >> 1;
  int kk0 = (ks & 1)*256;
  int c = ct*64 + lane;
  if (sec < 2){
    if (tid < 16){
      int b = b0 + tid;
      int p0 = (sec*64 + b)*8;
      float mv[8], lv[8];
      float M = -INFINITY;
      #pragma unroll
      for (int i=0;i<8;i++){
        mv[i] = ws[OFF_PML + (size_t)(p0+i)*2];
        lv[i] = ws[OFF_PML + (size_t)(p0+i)*2+1];
        M = fmaxf(M, mv[i]);
      }
      float L = 0.f, ev[8];
      #pragma unroll
      for (int i=0;i<8;i++){ ev[i] = __expf(mv[i]-M); L += lv[i]*ev[i]; }
      #pragma unroll
      for (int i=0;i<8;i++) ce_s[tid][i] = ev[i]/L;
    }
    __syncthreads();
  }
  #pragma unroll
  for (int i=0;i<4;i++){
    int flat = tid + i*256;
    int row = flat >> 6;
    int q   = flat & 63;
    int b = b0 + row;
    int h = kk0 + q*4;
    float4 v;
    if (sec < 2){
      int p0 = (sec*64 + b)*8;
      v.x = 0.f; v.y = 0.f; v.z = 0.f; v.w = 0.f;
      #pragma unroll
      for (int p=0;p<8;p++){
        float4 a = *(const float4*)(ws + OFF_PACC + (size_t)(p0+p)*HH + h);
        float cw = ce_s[row][p];
        v.x += a.x*cw; v.y += a.y*cw; v.z += a.z*cw; v.w += a.w*cw;
      }
    } else {
      size_t hoff = (sec==2 ? OFF_TH : OFF_XH) + (size_t)wsl*BB*HH;
      v = *(const float4*)(ws + hoff + (size_t)b*HH + h);
    }
    *(float4*)&comb_s[row][q*4] = v;
  }
  __syncthreads();
  float acc[4] = {0,0,0,0};
  #pragma unroll 4
  for (int k=0;k<256;k++){
    float wv = W_out[(size_t)(k0+k)*HH + c];
    #pragma unroll
    for (int i=0;i<4;i++) acc[i] += comb_s[wave*4+i][k]*wv;
  }
  #pragma unroll
  for (int i=0;i<4;i++){
    int b = b0 + wave*4 + i;
    ws[OFF_PART + ((size_t)ks*BB + b)*HH + c] = acc[i];
  }
}

// ---- per step: reduce 8 partials + tanh + store + O planes. grid 32 x 256 ----
__global__ __launch_bounds__(256) void k_outC(float* __restrict__ ws,
    float* __restrict__ dout, int t){
  int gid = blockIdx.x*256 + threadIdx.x;
  int b = gid >> 7, cq = gid & 127;
  int c0 = cq*4;
  float4 s = {0,0,0,0};
  #pragma unroll
  for (int ks=0;ks<8;ks++){
    float4 p = *(const float4*)(ws + OFF_PART + ((size_t)ks*BB + b)*HH + c0);
    s.x += p.x; s.y += p.y; s.z += p.z; s.w += p.w;
  }
  float4 o;
  o.x = tanhf(s.x); o.y = tanhf(s.y); o.z = tanhf(s.z); o.w = tanhf(s.w);
  *(float4*)(dout + ((size_t)b*TT + t)*HH + c0) = o;
  ushort4 h, l;
  split2(o.x,h.x,l.x); split2(o.y,h.y,l.y); split2(o.z,h.z,l.z); split2(o.w,h.w,l.w);
  unsigned short* oh = (unsigned short*)(ws + OFF_OH);
  unsigned short* ol = (unsigned short*)(ws + OFF_OL);
  *(ushort4*)(oh + (size_t)b*HH + c0) = h;
  *(ushort4*)(ol + (size_t)b*HH + c0) = l;
}

extern "C" void kernel_launch(void* const* d_in, const int* in_sizes, int n_in,
                              void* d_out, int out_size, void* d_ws, size_t ws_size,
                              hipStream_t stream){
  const int*   inp   = (const int*)  d_in[0];
  const float* emb0  = (const float*)d_in[1];
  const float* out0  = (const float*)d_in[2];
  const float* th0   = (const float*)d_in[3];
  const float* tc0   = (const float*)d_in[4];
  const float* trctx = (const float*)d_in[5];
  const float* xh0   = (const float*)d_in[6];
  const float* xc0   = (const float*)d_in[7];
  const float* txctx = (const float*)d_in[8];
  const float* wemb  = (const float*)d_in[9];
  const float* Wx    = (const float*)d_in[10];
  const float* Wh    = (const float*)d_in[11];
  const float* bias  = (const float*)d_in[12];
  const float* W_in  = (const float*)d_in[13];
  const float* W_out = (const float*)d_in[14];
  float* ws  = (float*)d_ws;
  float* out = (float*)d_out;
  unsigned short* wt_hi = (unsigned short*)(ws + OFF_WT_HI);
  unsigned short* wt_lo = (unsigned short*)(ws + OFF_WT_LO);
  unsigned short* wit_hi = (unsigned short*)(ws + OFF_WIT_HI);
  unsigned short* wit_lo = (unsigned short*)(ws + OFF_WIT_LO);
  unsigned short* eh = (unsigned short*)(ws + OFF_EH);
  unsigned short* el = (unsigned short*)(ws + OFF_EL);
  unsigned short* oh = (unsigned short*)(ws + OFF_OH);
  unsigned short* ol = (unsigned short*)(ws + OFF_OL);
  unsigned short* hhp = (unsigned short*)(ws + OFF_HHP);
  unsigned short* hlp = (unsigned short*)(ws + OFF_HLP);
  unsigned short* ctx16 = (unsigned short*)(ws + OFF_CTX16);
  float* gpart = ws + OFF_G;
  float* tgtp  = ws + OFF_TGTP;
  int use16 = (ws_size >= (size_t)WS_NEED_F * 4u) ? 1 : 0;

  hipLaunchKernelGGL(k_wprep,  dim3(768),   dim3(256), 0, stream, Wx, Wh, wt_hi, wt_lo);
  hipLaunchKernelGGL(k_wiprep, dim3(64),    dim3(256), 0, stream, W_in, wit_hi, wit_lo);
  if (use16)
    hipLaunchKernelGGL(k_ctx16, dim3(12800), dim3(256), 0, stream, trctx, txctx, ctx16);
  hipLaunchKernelGGL(k_prep,   dim3(TT*BB), dim3(128), 0, stream, inp, emb0, wemb, eh, el);
  hipLaunchKernelGGL(k_init,   dim3(160),   dim3(256), 0, stream, th0, tc0, xh0, xc0, out0, ws);
  for (int t=0; t<TT; t++){
    int rs = t & 1, wsl = rs ^ 1;
    hipLaunchKernelGGL(k_gemm, dim3(256),  dim3(256), 0, stream,
                       wt_hi, wt_lo, eh, el, oh, ol, hhp, hlp, gpart, t);
    hipLaunchKernelGGL(k_lstm, dim3(128),  dim3(256), 0, stream, ws, bias, rs);
    hipLaunchKernelGGL(k_tgtB, dim3(64),   dim3(256), 0, stream, wit_hi, wit_lo, hhp, hlp, tgtp);
    hipLaunchKernelGGL(k_attn, dim3(1024), dim3(256), 0, stream, trctx, txctx, ctx16, ws, use16);
    hipLaunchKernelGGL(k_outB, dim3(256),  dim3(256), 0, stream, W_out, ws, wsl);
    hipLaunchKernelGGL(k_outC, dim3(32),   dim3(256), 0, stream, ws, out, t);
  }
}

// Round 6
// 1896.174 us; speedup vs baseline: 5.3025x; 1.0597x over previous
//
#include <hip/hip_runtime.h>
#include <hip/hip_bf16.h>
#include <math.h>

#define BB 64
#define TT 32
#define HH 512
#define H2 1024
#define H4 2048
#define SS 400

// ---- workspace layout (float offsets) ----
#define OFF_WT_HI 0u          // WT hi: [2048 n][1536 k] bf16 = 1572864 floats
#define OFF_WT_LO 1572864u
#define OFF_WIT_HI 3145728u   // W_inT hi: [512 n][512 k] bf16 = 131072 floats
#define OFF_WIT_LO 3276800u
#define OFF_EH    3407872u    // E hi: [32][64][512] bf16
#define OFF_EL    3932160u
#define OFF_OH    4456448u    // O planes [64][512] bf16
#define OFF_OL    4472832u
#define OFF_HHP   4489216u    // h planes [2br*64][512] bf16
#define OFF_HLP   4521984u
#define OFF_TC    4554752u    // fp32 [2 slot][64][512]
#define OFF_XC    4620288u
#define OFF_TH    4685824u
#define OFF_XH    4751360u
#define OFF_G     4816896u    // [8ks][128][2048] fp32 = 2097152
#define OFF_TGTP  6914048u    // tgt partials [8ks][128][512] = 524288
#define OFF_PACC  7438336u    // [1024 pidx][512]
#define OFF_PML   7962624u    // [1024][2]
#define OFF_CTX16 7964672u    // bf16 ctx [2][64][400][512] = 13107200 float-slots
#define WS_NEED_F 21071872u
// MFMA-outB extension (capability-checked)
#define OFF_WOT_HI 21071872u  // W_outT hi: [512 n][2048 k] bf16 = 524288 floats
#define OFF_WOT_LO 21596160u
#define OFF_COMBH  22120448u  // comb hi: [64][1024] bf16 = 32768 floats
#define OFF_COMBL  22153216u
#define WS_NEED2_F 22185984u
#define OFF_PART  OFF_G       // k_out partials alias consumed G

typedef short bf16x8 __attribute__((ext_vector_type(8)));
typedef float f32x4  __attribute__((ext_vector_type(4)));

__device__ __forceinline__ float sigm(float x){ return 1.f/(1.f+__expf(-x)); }

__device__ __forceinline__ unsigned short bf_rn(float x){
  unsigned int u = __float_as_uint(x);
  return (unsigned short)((u + 0x7fffu + ((u>>16)&1u)) >> 16);
}
__device__ __forceinline__ void split2(float x, unsigned short &h, unsigned short &l){
  h = bf_rn(x);
  float hf = __uint_as_float(((unsigned int)h)<<16);
  l = bf_rn(x - hf);
}
__device__ __forceinline__ float blo(unsigned int u){ return __uint_as_float(u<<16); }
__device__ __forceinline__ float bhi(unsigned int u){ return __uint_as_float(u & 0xffff0000u); }

// ---- one-time: transpose W=[Wx;Wh] (1536x2048) -> WT[n][k] hi/lo bf16 ----
__global__ __launch_bounds__(256) void k_wprep(const float* __restrict__ Wx,
    const float* __restrict__ Wh, unsigned short* __restrict__ wt_hi,
    unsigned short* __restrict__ wt_lo){
  __shared__ float lds[64][68];
  int bk = blockIdx.x >> 5, bn = blockIdx.x & 31;
  int k0 = bk*64, n0 = bn*64;
  int tid = threadIdx.x;
  #pragma unroll
  for (int i=0;i<4;i++){
    int flat = tid + i*256;
    int k = flat >> 4, nq = flat & 15;
    int kg = k0 + k;
    const float* srow = (kg < 1024) ? Wx + (size_t)kg*H4 : Wh + (size_t)(kg-1024)*H4;
    float4 v = *(const float4*)(srow + n0 + nq*4);
    *(float4*)&lds[k][nq*4] = v;
  }
  __syncthreads();
  #pragma unroll
  for (int i=0;i<2;i++){
    int flat = tid + i*256;
    int n = flat >> 3, k8 = flat & 7;
    ushort4 h0, h1, l0, l1;
    unsigned short h[8], l[8];
    #pragma unroll
    for (int j=0;j<8;j++) split2(lds[k8*8+j][n], h[j], l[j]);
    h0.x=h[0];h0.y=h[1];h0.z=h[2];h0.w=h[3]; h1.x=h[4];h1.y=h[5];h1.z=h[6];h1.w=h[7];
    l0.x=l[0];l0.y=l[1];l0.z=l[2];l0.w=l[3]; l1.x=l[4];l1.y=l[5];l1.z=l[6];l1.w=l[7];
    size_t dst = (size_t)(n0+n)*1536 + k0 + k8*8;
    *(ushort4*)(wt_hi+dst) = h0; *(ushort4*)(wt_hi+dst+4) = h1;
    *(ushort4*)(wt_lo+dst) = l0; *(ushort4*)(wt_lo+dst+4) = l1;
  }
}

// ---- one-time: transpose W_in (512x512) -> WIT[n][k] hi/lo bf16 ----
__global__ __launch_bounds__(256) void k_wiprep(const float* __restrict__ W_in,
    unsigned short* __restrict__ wit_hi, unsigned short* __restrict__ wit_lo){
  __shared__ float lds[64][68];
  int bk = blockIdx.x >> 3, bn = blockIdx.x & 7;
  int k0 = bk*64, n0 = bn*64;
  int tid = threadIdx.x;
  #pragma unroll
  for (int i=0;i<4;i++){
    int flat = tid + i*256;
    int k = flat >> 4, nq = flat & 15;
    float4 v = *(const float4*)(W_in + (size_t)(k0+k)*HH + n0 + nq*4);
    *(float4*)&lds[k][nq*4] = v;
  }
  __syncthreads();
  #pragma unroll
  for (int i=0;i<2;i++){
    int flat = tid + i*256;
    int n = flat >> 3, k8 = flat & 7;
    ushort4 h0, h1, l0, l1;
    unsigned short h[8], l[8];
    #pragma unroll
    for (int j=0;j<8;j++) split2(lds[k8*8+j][n], h[j], l[j]);
    h0.x=h[0];h0.y=h[1];h0.z=h[2];h0.w=h[3]; h1.x=h[4];h1.y=h[5];h1.z=h[6];h1.w=h[7];
    l0.x=l[0];l0.y=l[1];l0.z=l[2];l0.w=l[3]; l1.x=l[4];l1.y=l[5];l1.z=l[6];l1.w=l[7];
    size_t dst = (size_t)(n0+n)*HH + k0 + k8*8;
    *(ushort4*)(wit_hi+dst) = h0; *(ushort4*)(wit_hi+dst+4) = h1;
    *(ushort4*)(wit_lo+dst) = l0; *(ushort4*)(wit_lo+dst+4) = l1;
  }
}

// ---- one-time: transpose W_out (2048x512) -> WOT[n][k] hi/lo bf16 ----
__global__ __launch_bounds__(256) void k_woprep(const float* __restrict__ W_out,
    unsigned short* __restrict__ wot_hi, unsigned short* __restrict__ wot_lo){
  __shared__ float lds[64][68];
  int bk = blockIdx.x >> 3, bn = blockIdx.x & 7;   // bk 0..31, bn 0..7
  int k0 = bk*64, n0 = bn*64;
  int tid = threadIdx.x;
  #pragma unroll
  for (int i=0;i<4;i++){
    int flat = tid + i*256;
    int k = flat >> 4, nq = flat & 15;
    float4 v = *(const float4*)(W_out + (size_t)(k0+k)*HH + n0 + nq*4);
    *(float4*)&lds[k][nq*4] = v;
  }
  __syncthreads();
  #pragma unroll
  for (int i=0;i<2;i++){
    int flat = tid + i*256;
    int n = flat >> 3, k8 = flat & 7;
    ushort4 h0, h1, l0, l1;
    unsigned short h[8], l[8];
    #pragma unroll
    for (int j=0;j<8;j++) split2(lds[k8*8+j][n], h[j], l[j]);
    h0.x=h[0];h0.y=h[1];h0.z=h[2];h0.w=h[3]; h1.x=h[4];h1.y=h[5];h1.z=h[6];h1.w=h[7];
    l0.x=l[0];l0.y=l[1];l0.z=l[2];l0.w=l[3]; l1.x=l[4];l1.y=l[5];l1.z=l[6];l1.w=l[7];
    size_t dst = (size_t)(n0+n)*H4 + k0 + k8*8;
    *(ushort4*)(wot_hi+dst) = h0; *(ushort4*)(wot_hi+dst+4) = h1;
    *(ushort4*)(wot_lo+dst) = l0; *(ushort4*)(wot_lo+dst+4) = l1;
  }
}

// ---- one-time: both contexts -> bf16. grid 12800 x 256 ----
__global__ __launch_bounds__(256) void k_ctx16(const float* __restrict__ trctx,
    const float* __restrict__ txctx, unsigned short* __restrict__ ctx16){
  size_t gid = (size_t)blockIdx.x*256 + threadIdx.x;
  size_t off = gid*8;
  const size_t CH = (size_t)BB*SS*HH;
  const float* src = (off < CH) ? trctx + off : txctx + (off - CH);
  float4 a = *(const float4*)src;
  float4 c = *(const float4*)(src+4);
  ushort4 u0, u1;
  u0.x=bf_rn(a.x); u0.y=bf_rn(a.y); u0.z=bf_rn(a.z); u0.w=bf_rn(a.w);
  u1.x=bf_rn(c.x); u1.y=bf_rn(c.y); u1.z=bf_rn(c.z); u1.w=bf_rn(c.w);
  *(ushort4*)(ctx16+off) = u0;
  *(ushort4*)(ctx16+off+4) = u1;
}

// ---- one-time: embeddings -> hi/lo planes for all t ----
__global__ __launch_bounds__(128) void k_prep(const int* __restrict__ inp,
    const float* __restrict__ emb0, const float* __restrict__ wemb,
    unsigned short* __restrict__ eh, unsigned short* __restrict__ el){
  int n = blockIdx.x; int t = n >> 6, b = n & 63;
  const float* src = (t==0) ? emb0 + (size_t)b*HH
                            : wemb + (size_t)inp[b*TT + (t-1)]*HH;
  float4 v = ((const float4*)src)[threadIdx.x];
  ushort4 h, l;
  split2(v.x,h.x,l.x); split2(v.y,h.y,l.y); split2(v.z,h.z,l.z); split2(v.w,h.w,l.w);
  size_t base = ((size_t)t*BB + b)*HH + threadIdx.x*4;
  *(ushort4*)(eh+base) = h; *(ushort4*)(el+base) = l;
}

// ---- one-time: state init ----
__global__ __launch_bounds__(256) void k_init(const float* __restrict__ th0,
    const float* __restrict__ tc0, const float* __restrict__ xh0,
    const float* __restrict__ xc0, const float* __restrict__ out0,
    float* __restrict__ ws){
  unsigned short* hhp = (unsigned short*)(ws + OFF_HHP);
  unsigned short* hlp = (unsigned short*)(ws + OFF_HLP);
  unsigned short* oh  = (unsigned short*)(ws + OFF_OH);
  unsigned short* ol  = (unsigned short*)(ws + OFF_OL);
  int which = blockIdx.x >> 5;
  int idx = (blockIdx.x & 31)*256 + threadIdx.x;
  if (which==0){ ((float4*)(ws+OFF_TC))[idx] = ((const float4*)tc0)[idx]; return; }
  if (which==1){ ((float4*)(ws+OFF_XC))[idx] = ((const float4*)xc0)[idx]; return; }
  const float* s = which==2? th0 : which==3? xh0 : out0;
  float4 v = ((const float4*)s)[idx];
  ushort4 h, l;
  split2(v.x,h.x,l.x); split2(v.y,h.y,l.y); split2(v.z,h.z,l.z); split2(v.w,h.w,l.w);
  if (which==4){
    *(ushort4*)(oh + (size_t)idx*4) = h; *(ushort4*)(ol + (size_t)idx*4) = l;
  } else {
    size_t base = (size_t)(which-2)*BB*HH + (size_t)idx*4;
    *(ushort4*)(hhp+base) = h; *(ushort4*)(hlp+base) = l;
  }
}

// ---- per step: MFMA gate GEMM. grid 256 = bn(32) x ks(8), 256 thr ----
__global__ __launch_bounds__(256) void k_gemm(const unsigned short* __restrict__ wt_hi,
    const unsigned short* __restrict__ wt_lo, const unsigned short* __restrict__ eh,
    const unsigned short* __restrict__ el, const unsigned short* __restrict__ oh,
    const unsigned short* __restrict__ ol, const unsigned short* __restrict__ hhp,
    const unsigned short* __restrict__ hlp, float* __restrict__ gpart, int t){
  int tid = threadIdx.x, lane = tid & 63, wave = tid >> 6;
  int bn = blockIdx.x & 31, ks = blockIdx.x >> 5;
  int lm = lane & 15, lk = (lane >> 4) << 3;
  f32x4 acc[2][4];
  #pragma unroll
  for (int i=0;i<2;i++)
    #pragma unroll
    for (int j=0;j<4;j++) acc[i][j] = (f32x4){0.f,0.f,0.f,0.f};
  size_t ebase[2], obase[2], hbase[2];
  #pragma unroll
  for (int i=0;i<2;i++){
    int r = (wave*2 + i)*16 + lm;
    int b = r & 63, br = r >> 6;
    ebase[i] = ((size_t)t*BB + b)*HH;
    obase[i] = (size_t)b*HH;
    hbase[i] = ((size_t)br*BB + b)*HH;
  }
  size_t wb[4];
  #pragma unroll
  for (int j=0;j<4;j++) wb[j] = (size_t)(bn*64 + j*16 + lm)*1536;
  #pragma unroll
  for (int c=0;c<6;c++){
    int kc = ks*192 + c*32;
    int sec = kc >> 9;
    int kk = (kc & 511) + lk;
    const unsigned short* ph = sec==0? eh : sec==1? oh : hhp;
    const unsigned short* pl = sec==0? el : sec==1? ol : hlp;
    bf16x8 ah[2], al[2], wh_[4], wl_[4];
    #pragma unroll
    for (int i=0;i<2;i++){
      size_t off = (sec==0? ebase[i] : sec==1? obase[i] : hbase[i]) + kk;
      ah[i] = *(const bf16x8*)(ph + off);
      al[i] = *(const bf16x8*)(pl + off);
    }
    int kw = kc + lk;
    #pragma unroll
    for (int j=0;j<4;j++){
      wh_[j] = *(const bf16x8*)(wt_hi + wb[j] + kw);
      wl_[j] = *(const bf16x8*)(wt_lo + wb[j] + kw);
    }
    #pragma unroll
    for (int i=0;i<2;i++)
      #pragma unroll
      for (int j=0;j<4;j++){
        acc[i][j] = __builtin_amdgcn_mfma_f32_16x16x32_bf16(ah[i], wh_[j], acc[i][j], 0,0,0);
        acc[i][j] = __builtin_amdgcn_mfma_f32_16x16x32_bf16(ah[i], wl_[j], acc[i][j], 0,0,0);
        acc[i][j] = __builtin_amdgcn_mfma_f32_16x16x32_bf16(al[i], wh_[j], acc[i][j], 0,0,0);
      }
  }
  int lr4 = (lane >> 4) * 4;
  #pragma unroll
  for (int i=0;i<2;i++){
    int m0 = (wave*2+i)*16;
    #pragma unroll
    for (int j=0;j<4;j++){
      int col = bn*64 + j*16 + lm;
      #pragma unroll
      for (int q=0;q<4;q++){
        int row = m0 + lr4 + q;
        gpart[((size_t)ks*128 + row)*H4 + col] = acc[i][j][q];
      }
    }
  }
}

// ---- per step: 8-way partial reduce + LSTM pointwise. grid 128 x 256 ----
__global__ __launch_bounds__(256) void k_lstm(float* __restrict__ ws,
    const float* __restrict__ bias, int rs){
  int gid = blockIdx.x*256 + threadIdx.x;
  int b = gid >> 9, j = gid & 511;
  int wsl = rs ^ 1;
  const float* gp = ws + OFF_G;
  unsigned short* hhp = (unsigned short*)(ws + OFF_HHP);
  unsigned short* hlp = (unsigned short*)(ws + OFF_HLP);
  #pragma unroll
  for (int br=0;br<2;br++){
    float g0=0.f,g1=0.f,g2=0.f,g3=0.f;
    #pragma unroll
    for (int ks=0;ks<8;ks++){
      size_t base = ((size_t)ks*128 + br*64 + b)*H4 + j;
      g0 += gp[base]; g1 += gp[base+512]; g2 += gp[base+1024]; g3 += gp[base+1536];
    }
    g0 += bias[j]; g1 += bias[512+j]; g2 += bias[1024+j]; g3 += bias[1536+j];
    size_t hoff = (br? OFF_XH : OFF_TH), coff = (br? OFF_XC : OFF_TC);
    float cold = ws[coff + (size_t)rs*BB*HH + (size_t)b*HH + j];
    float cn = sigm(g1)*cold + sigm(g0)*tanhf(g2);
    float hn = sigm(g3)*tanhf(cn);
    ws[coff + (size_t)wsl*BB*HH + (size_t)b*HH + j] = cn;
    ws[hoff + (size_t)wsl*BB*HH + (size_t)b*HH + j] = hn;
    unsigned short h_, l_;
    split2(hn, h_, l_);
    hhp[(size_t)(br*64+b)*HH + j] = h_;
    hlp[(size_t)(br*64+b)*HH + j] = l_;
  }
}

// ---- per step: MFMA tgt partials = h @ W_in. grid 64 = cn(8) x ks(8) ----
__global__ __launch_bounds__(256) void k_tgtB(const unsigned short* __restrict__ wit_hi,
    const unsigned short* __restrict__ wit_lo, const unsigned short* __restrict__ hhp,
    const unsigned short* __restrict__ hlp, float* __restrict__ tgtp){
  int tid = threadIdx.x, lane = tid & 63, wave = tid >> 6;
  int cn = blockIdx.x & 7, ks = blockIdx.x >> 3;
  int lm = lane & 15, lk = (lane >> 4) << 3;
  f32x4 acc[2][4];
  #pragma unroll
  for (int i=0;i<2;i++)
    #pragma unroll
    for (int j=0;j<4;j++) acc[i][j] = (f32x4){0.f,0.f,0.f,0.f};
  size_t abase[2];
  #pragma unroll
  for (int i=0;i<2;i++) abase[i] = (size_t)(wave*32 + i*16 + lm)*HH;
  size_t wb[4];
  #pragma unroll
  for (int j=0;j<4;j++) wb[j] = (size_t)(cn*64 + j*16 + lm)*HH;
  #pragma unroll
  for (int c=0;c<2;c++){
    int kc = ks*64 + c*32;
    bf16x8 ah[2], al[2], wh_[4], wl_[4];
    #pragma unroll
    for (int i=0;i<2;i++){
      ah[i] = *(const bf16x8*)(hhp + abase[i] + kc + lk);
      al[i] = *(const bf16x8*)(hlp + abase[i] + kc + lk);
    }
    #pragma unroll
    for (int j=0;j<4;j++){
      wh_[j] = *(const bf16x8*)(wit_hi + wb[j] + kc + lk);
      wl_[j] = *(const bf16x8*)(wit_lo + wb[j] + kc + lk);
    }
    #pragma unroll
    for (int i=0;i<2;i++)
      #pragma unroll
      for (int j=0;j<4;j++){
        acc[i][j] = __builtin_amdgcn_mfma_f32_16x16x32_bf16(ah[i], wh_[j], acc[i][j], 0,0,0);
        acc[i][j] = __builtin_amdgcn_mfma_f32_16x16x32_bf16(ah[i], wl_[j], acc[i][j], 0,0,0);
        acc[i][j] = __builtin_amdgcn_mfma_f32_16x16x32_bf16(al[i], wh_[j], acc[i][j], 0,0,0);
      }
  }
  int lr4 = (lane >> 4) * 4;
  #pragma unroll
  for (int i=0;i<2;i++){
    int m0 = wave*32 + i*16;
    #pragma unroll
    for (int j=0;j<4;j++){
      int col = cn*64 + j*16 + lm;
      #pragma unroll
      for (int q=0;q<4;q++){
        int row = m0 + lr4 + q;
        tgtp[((size_t)ks*128 + row)*HH + col] = acc[i][j][q];
      }
    }
  }
}

// ---- per step: two-pass flash attention partial.
// grid 1024, decode for SEQUENTIAL streaming: sh=blk&7, b=(blk>>3)&63, branch=blk>>9
__global__ __launch_bounds__(256) void k_attn(const float* __restrict__ tree_ctx,
    const float* __restrict__ text_ctx, const unsigned short* __restrict__ ctx16,
    float* __restrict__ ws, int use16){
  int blk = blockIdx.x;
  int sh = blk & 7, b = (blk>>3) & 63, branch = blk >> 9;
  int tid = threadIdx.x, lane = tid & 63, wave = tid >> 6;
  __shared__ float tgt_s[512];
  __shared__ float sc_s[64];
  __shared__ float w_s[64];
  int row128 = branch*64 + b;
  if (tid < 128){
    float4 s = {0,0,0,0};
    #pragma unroll
    for (int p=0;p<8;p++){
      float4 v = *(const float4*)(ws + OFF_TGTP + ((size_t)p*128 + row128)*HH + tid*4);
      s.x += v.x; s.y += v.y; s.z += v.z; s.w += v.w;
    }
    ((float4*)tgt_s)[tid] = s;
  }
  if (tid >= 128 && tid < 192) sc_s[tid-128] = -INFINITY;
  __syncthreads();
  const size_t CH = (size_t)BB*SS*HH;
  const float* ctxf = (branch? text_ctx : tree_ctx) + ((size_t)b*SS + sh*50)*HH;
  const unsigned short* c16 = ctx16 + (branch? CH:0) + ((size_t)b*SS + sh*50)*HH;
  // pass 1: scores
  float4 ta = *(const float4*)&tgt_s[lane*8];
  float4 tb = *(const float4*)&tgt_s[lane*8+4];
  if (use16){
    for (int r = wave; r < 50; r += 4){
      uint4 u = *(const uint4*)(c16 + (size_t)r*HH + lane*8);
      float p = blo(u.x)*ta.x + bhi(u.x)*ta.y + blo(u.y)*ta.z + bhi(u.y)*ta.w
              + blo(u.z)*tb.x + bhi(u.z)*tb.y + blo(u.w)*tb.z + bhi(u.w)*tb.w;
      #pragma unroll
      for (int off=32; off; off>>=1) p += __shfl_xor(p, off, 64);
      if (lane==0) sc_s[r] = p;
    }
  } else {
    for (int r = wave; r < 50; r += 4){
      const float* crow = ctxf + (size_t)r*HH + lane*8;
      float4 ca = *(const float4*)crow;
      float4 cb = *(const float4*)(crow+4);
      float p = ca.x*ta.x + ca.y*ta.y + ca.z*ta.z + ca.w*ta.w
              + cb.x*tb.x + cb.y*tb.y + cb.z*tb.z + cb.w*tb.w;
      #pragma unroll
      for (int off=32; off; off>>=1) p += __shfl_xor(p, off, 64);
      if (lane==0) sc_s[r] = p;
    }
  }
  __syncthreads();
  // wave 0: softmax partial (m, l), unnormalized weights -> LDS
  if (wave==0){
    float s = sc_s[lane];
    float m = s;
    #pragma unroll
    for (int off=32; off; off>>=1) m = fmaxf(m, __shfl_xor(m, off, 64));
    float e = (lane<50)? __expf(s-m) : 0.f;
    w_s[lane] = e;
    float l = e;
    #pragma unroll
    for (int off=32; off; off>>=1) l += __shfl_xor(l, off, 64);
    if (lane==0){
      int pidx = (branch*64 + b)*8 + sh;
      ws[OFF_PML + (size_t)pidx*2]   = m;
      ws[OFF_PML + (size_t)pidx*2+1] = l;
    }
  }
  __syncthreads();
  // pass 2: weighted sum, thread owns 2 columns
  int c0 = tid*2;
  float a0 = 0.f, a1 = 0.f;
  if (use16){
    #pragma unroll 10
    for (int s=0;s<50;s++){
      float w = w_s[s];
      unsigned int u = *(const unsigned int*)(c16 + (size_t)s*HH + c0);
      a0 += w*blo(u); a1 += w*bhi(u);
    }
  } else {
    #pragma unroll 10
    for (int s=0;s<50;s++){
      float w = w_s[s];
      float2 v = *(const float2*)(ctxf + (size_t)s*HH + c0);
      a0 += w*v.x; a1 += w*v.y;
    }
  }
  int pidx = (branch*64 + b)*8 + sh;
  float2 o; o.x = a0; o.y = a1;
  *(float2*)(ws + OFF_PACC + (size_t)pidx*HH + c0) = o;
}

// ---- per step: merge attn partials -> comb hi/lo bf16 [64][1024]. grid 64 ----
__global__ __launch_bounds__(256) void k_outA(float* __restrict__ ws){
  __shared__ float ce_s[2][8];
  int b = blockIdx.x, tid = threadIdx.x;
  if (tid < 2){
    int p0 = (tid*64 + b)*8;
    float mv[8], lv[8];
    float M = -INFINITY;
    #pragma unroll
    for (int i=0;i<8;i++){
      mv[i] = ws[OFF_PML + (size_t)(p0+i)*2];
      lv[i] = ws[OFF_PML + (size_t)(p0+i)*2+1];
      M = fmaxf(M, mv[i]);
    }
    float L = 0.f, ev[8];
    #pragma unroll
    for (int i=0;i<8;i++){ ev[i] = __expf(mv[i]-M); L += lv[i]*ev[i]; }
    #pragma unroll
    for (int i=0;i<8;i++) ce_s[tid][i] = ev[i]/L;
  }
  __syncthreads();
  int h = tid*4;                 // 0..1023
  int sec = h >> 9, hs = h & 511;
  int p0 = (sec*64 + b)*8;
  float4 v = {0,0,0,0};
  #pragma unroll
  for (int p=0;p<8;p++){
    float4 a = *(const float4*)(ws + OFF_PACC + (size_t)(p0+p)*HH + hs);
    float cw = ce_s[sec][p];
    v.x += a.x*cw; v.y += a.y*cw; v.z += a.z*cw; v.w += a.w*cw;
  }
  ushort4 hv, lv;
  split2(v.x,hv.x,lv.x); split2(v.y,hv.y,lv.y); split2(v.z,hv.z,lv.z); split2(v.w,hv.w,lv.w);
  unsigned short* ch = (unsigned short*)(ws + OFF_COMBH);
  unsigned short* cl = (unsigned short*)(ws + OFF_COMBL);
  *(ushort4*)(ch + (size_t)b*1024 + h) = hv;
  *(ushort4*)(cl + (size_t)b*1024 + h) = lv;
}

// ---- per step: MFMA out partials = comb @ W_out. grid 64 = nt(8) x ks(8) ----
__global__ __launch_bounds__(256) void k_outBm(const unsigned short* __restrict__ wot_hi,
    const unsigned short* __restrict__ wot_lo, const unsigned short* __restrict__ combh,
    const unsigned short* __restrict__ combl, const unsigned short* __restrict__ hhp,
    const unsigned short* __restrict__ hlp, float* __restrict__ part){
  int tid = threadIdx.x, lane = tid & 63, wave = tid >> 6;
  int nt = blockIdx.x & 7, ks = blockIdx.x >> 3;
  int lm = lane & 15, lk = (lane >> 4) << 3;
  f32x4 acc[4];
  #pragma unroll
  for (int m=0;m<4;m++) acc[m] = (f32x4){0.f,0.f,0.f,0.f};
  size_t wb = (size_t)(nt*64 + wave*16 + lm)*H4;
  #pragma unroll
  for (int c=0;c<8;c++){
    int kg = ks*256 + c*32;
    int sec = kg >> 9;                 // 0,1: comb planes; 2,3: th/xh planes
    bf16x8 wh_ = *(const bf16x8*)(wot_hi + wb + kg + lk);
    bf16x8 wl_ = *(const bf16x8*)(wot_lo + wb + kg + lk);
    #pragma unroll
    for (int m=0;m<4;m++){
      int row = m*16 + lm;             // batch b 0..63
      bf16x8 ah, al;
      if (sec < 2){
        size_t off = (size_t)row*1024 + kg + lk;
        ah = *(const bf16x8*)(combh + off);
        al = *(const bf16x8*)(combl + off);
      } else {
        size_t off = ((size_t)(sec-2)*64 + row)*HH + (kg & 511) + lk;
        ah = *(const bf16x8*)(hhp + off);
        al = *(const bf16x8*)(hlp + off);
      }
      acc[m] = __builtin_amdgcn_mfma_f32_16x16x32_bf16(ah, wh_, acc[m], 0,0,0);
      acc[m] = __builtin_amdgcn_mfma_f32_16x16x32_bf16(ah, wl_, acc[m], 0,0,0);
      acc[m] = __builtin_amdgcn_mfma_f32_16x16x32_bf16(al, wh_, acc[m], 0,0,0);
    }
  }
  int lr4 = (lane >> 4) * 4;
  int col = nt*64 + wave*16 + lm;
  #pragma unroll
  for (int m=0;m<4;m++){
    #pragma unroll
    for (int q=0;q<4;q++){
      int b = m*16 + lr4 + q;
      part[((size_t)ks*BB + b)*HH + col] = acc[m][q];
    }
  }
}

// ---- per step (fallback): fp32 split-K GEMM out = combined @ W_out. grid 256 ----
__global__ __launch_bounds__(256) void k_outB(const float* __restrict__ W_out,
    float* __restrict__ ws, int wsl){
  __shared__ float comb_s[16][256];
  __shared__ float ce_s[16][8];
  int tid = threadIdx.x, lane = tid & 63, wave = tid >> 6;
  int blk = blockIdx.x;
  int ct = blk & 7, bg = (blk>>3)&3, ks = blk>>5;
  int b0 = bg*16;
  int k0 = ks*256;
  int sec = ks >> 1;
  int kk0 = (ks & 1)*256;
  int c = ct*64 + lane;
  if (sec < 2){
    if (tid < 16){
      int b = b0 + tid;
      int p0 = (sec*64 + b)*8;
      float mv[8], lv[8];
      float M = -INFINITY;
      #pragma unroll
      for (int i=0;i<8;i++){
        mv[i] = ws[OFF_PML + (size_t)(p0+i)*2];
        lv[i] = ws[OFF_PML + (size_t)(p0+i)*2+1];
        M = fmaxf(M, mv[i]);
      }
      float L = 0.f, ev[8];
      #pragma unroll
      for (int i=0;i<8;i++){ ev[i] = __expf(mv[i]-M); L += lv[i]*ev[i]; }
      #pragma unroll
      for (int i=0;i<8;i++) ce_s[tid][i] = ev[i]/L;
    }
    __syncthreads();
  }
  #pragma unroll
  for (int i=0;i<4;i++){
    int flat = tid + i*256;
    int row = flat >> 6;
    int q   = flat & 63;
    int b = b0 + row;
    int h = kk0 + q*4;
    float4 v;
    if (sec < 2){
      int p0 = (sec*64 + b)*8;
      v.x = 0.f; v.y = 0.f; v.z = 0.f; v.w = 0.f;
      #pragma unroll
      for (int p=0;p<8;p++){
        float4 a = *(const float4*)(ws + OFF_PACC + (size_t)(p0+p)*HH + h);
        float cw = ce_s[row][p];
        v.x += a.x*cw; v.y += a.y*cw; v.z += a.z*cw; v.w += a.w*cw;
      }
    } else {
      size_t hoff = (sec==2 ? OFF_TH : OFF_XH) + (size_t)wsl*BB*HH;
      v = *(const float4*)(ws + hoff + (size_t)b*HH + h);
    }
    *(float4*)&comb_s[row][q*4] = v;
  }
  __syncthreads();
  float acc[4] = {0,0,0,0};
  #pragma unroll 4
  for (int k=0;k<256;k++){
    float wv = W_out[(size_t)(k0+k)*HH + c];
    #pragma unroll
    for (int i=0;i<4;i++) acc[i] += comb_s[wave*4+i][k]*wv;
  }
  #pragma unroll
  for (int i=0;i<4;i++){
    int b = b0 + wave*4 + i;
    ws[OFF_PART + ((size_t)ks*BB + b)*HH + c] = acc[i];
  }
}

// ---- per step: reduce 8 partials + tanh + store + O planes. grid 32 x 256 ----
__global__ __launch_bounds__(256) void k_outC(float* __restrict__ ws,
    float* __restrict__ dout, int t){
  int gid = blockIdx.x*256 + threadIdx.x;
  int b = gid >> 7, cq = gid & 127;
  int c0 = cq*4;
  float4 s = {0,0,0,0};
  #pragma unroll
  for (int ks=0;ks<8;ks++){
    float4 p = *(const float4*)(ws + OFF_PART + ((size_t)ks*BB + b)*HH + c0);
    s.x += p.x; s.y += p.y; s.z += p.z; s.w += p.w;
  }
  float4 o;
  o.x = tanhf(s.x); o.y = tanhf(s.y); o.z = tanhf(s.z); o.w = tanhf(s.w);
  *(float4*)(dout + ((size_t)b*TT + t)*HH + c0) = o;
  ushort4 h, l;
  split2(o.x,h.x,l.x); split2(o.y,h.y,l.y); split2(o.z,h.z,l.z); split2(o.w,h.w,l.w);
  unsigned short* oh = (unsigned short*)(ws + OFF_OH);
  unsigned short* ol = (unsigned short*)(ws + OFF_OL);
  *(ushort4*)(oh + (size_t)b*HH + c0) = h;
  *(ushort4*)(ol + (size_t)b*HH + c0) = l;
}

extern "C" void kernel_launch(void* const* d_in, const int* in_sizes, int n_in,
                              void* d_out, int out_size, void* d_ws, size_t ws_size,
                              hipStream_t stream){
  const int*   inp   = (const int*)  d_in[0];
  const float* emb0  = (const float*)d_in[1];
  const float* out0  = (const float*)d_in[2];
  const float* th0   = (const float*)d_in[3];
  const float* tc0   = (const float*)d_in[4];
  const float* trctx = (const float*)d_in[5];
  const float* xh0   = (const float*)d_in[6];
  const float* xc0   = (const float*)d_in[7];
  const float* txctx = (const float*)d_in[8];
  const float* wemb  = (const float*)d_in[9];
  const float* Wx    = (const float*)d_in[10];
  const float* Wh    = (const float*)d_in[11];
  const float* bias  = (const float*)d_in[12];
  const float* W_in  = (const float*)d_in[13];
  const float* W_out = (const float*)d_in[14];
  float* ws  = (float*)d_ws;
  float* out = (float*)d_out;
  unsigned short* wt_hi = (unsigned short*)(ws + OFF_WT_HI);
  unsigned short* wt_lo = (unsigned short*)(ws + OFF_WT_LO);
  unsigned short* wit_hi = (unsigned short*)(ws + OFF_WIT_HI);
  unsigned short* wit_lo = (unsigned short*)(ws + OFF_WIT_LO);
  unsigned short* wot_hi = (unsigned short*)(ws + OFF_WOT_HI);
  unsigned short* wot_lo = (unsigned short*)(ws + OFF_WOT_LO);
  unsigned short* combh = (unsigned short*)(ws + OFF_COMBH);
  unsigned short* combl = (unsigned short*)(ws + OFF_COMBL);
  unsigned short* eh = (unsigned short*)(ws + OFF_EH);
  unsigned short* el = (unsigned short*)(ws + OFF_EL);
  unsigned short* oh = (unsigned short*)(ws + OFF_OH);
  unsigned short* ol = (unsigned short*)(ws + OFF_OL);
  unsigned short* hhp = (unsigned short*)(ws + OFF_HHP);
  unsigned short* hlp = (unsigned short*)(ws + OFF_HLP);
  unsigned short* ctx16 = (unsigned short*)(ws + OFF_CTX16);
  float* gpart = ws + OFF_G;
  float* tgtp  = ws + OFF_TGTP;
  float* part  = ws + OFF_PART;
  int use16 = (ws_size >= (size_t)WS_NEED_F  * 4u) ? 1 : 0;
  int useMf = (ws_size >= (size_t)WS_NEED2_F * 4u) ? 1 : 0;

  hipLaunchKernelGGL(k_wprep,  dim3(768),   dim3(256), 0, stream, Wx, Wh, wt_hi, wt_lo);
  hipLaunchKernelGGL(k_wiprep, dim3(64),    dim3(256), 0, stream, W_in, wit_hi, wit_lo);
  if (useMf)
    hipLaunchKernelGGL(k_woprep, dim3(256), dim3(256), 0, stream, W_out, wot_hi, wot_lo);
  if (use16)
    hipLaunchKernelGGL(k_ctx16, dim3(12800), dim3(256), 0, stream, trctx, txctx, ctx16);
  hipLaunchKernelGGL(k_prep,   dim3(TT*BB), dim3(128), 0, stream, inp, emb0, wemb, eh, el);
  hipLaunchKernelGGL(k_init,   dim3(160),   dim3(256), 0, stream, th0, tc0, xh0, xc0, out0, ws);
  for (int t=0; t<TT; t++){
    int rs = t & 1, wsl = rs ^ 1;
    hipLaunchKernelGGL(k_gemm, dim3(256),  dim3(256), 0, stream,
                       wt_hi, wt_lo, eh, el, oh, ol, hhp, hlp, gpart, t);
    hipLaunchKernelGGL(k_lstm, dim3(128),  dim3(256), 0, stream, ws, bias, rs);
    hipLaunchKernelGGL(k_tgtB, dim3(64),   dim3(256), 0, stream, wit_hi, wit_lo, hhp, hlp, tgtp);
    hipLaunchKernelGGL(k_attn, dim3(1024), dim3(256), 0, stream, trctx, txctx, ctx16, ws, use16);
    if (useMf){
      hipLaunchKernelGGL(k_outA,  dim3(64), dim3(256), 0, stream, ws);
      hipLaunchKernelGGL(k_outBm, dim3(64), dim3(256), 0, stream,
                         wot_hi, wot_lo, combh, combl, hhp, hlp, part);
    } else {
      hipLaunchKernelGGL(k_outB, dim3(256), dim3(256), 0, stream, W_out, ws, wsl);
    }
    hipLaunchKernelGGL(k_outC, dim3(32),   dim3(256), 0, stream, ws, out, t);
  }
}

// Round 7
// 1878.466 us; speedup vs baseline: 5.3525x; 1.0094x over previous
//
#include <hip/hip_runtime.h>
#include <hip/hip_bf16.h>
#include <math.h>

#define BB 64
#define TT 32
#define HH 512
#define H2 1024
#define H4 2048
#define SS 400

// ---- workspace layout (float offsets) ----
#define OFF_WT_HI 0u          // WT hi: [2048 n][1536 k] bf16 = 1572864 floats
#define OFF_WT_LO 1572864u
#define OFF_WIT_HI 3145728u   // W_inT hi: [512 n][512 k] bf16 = 131072 floats
#define OFF_WIT_LO 3276800u
#define OFF_EH    3407872u    // E hi: [32][64][512] bf16
#define OFF_EL    3932160u
#define OFF_OH    4456448u    // O planes [64][512] bf16
#define OFF_OL    4472832u
#define OFF_HHP   4489216u    // h planes [2br*64][512] bf16
#define OFF_HLP   4521984u
#define OFF_TC    4554752u    // fp32 [2 slot][64][512]
#define OFF_XC    4620288u
#define OFF_TH    4685824u
#define OFF_XH    4751360u
#define OFF_G     4816896u    // [8ks][128][2048] fp32 = 2097152
#define OFF_TGTP  6914048u    // tgt partials [8ks][128][512] = 524288
#define OFF_PACC  7438336u    // [1024 pidx][512]
#define OFF_PML   7962624u    // [1024][2]
#define OFF_CTX16 7964672u    // bf16 ctx [2][64][400][512] = 13107200 float-slots
#define WS_NEED_F 21071872u
// MFMA-outB extension (capability-checked)
#define OFF_WOT_HI 21071872u  // W_outT hi: [512 n][2048 k] bf16 = 524288 floats
#define OFF_WOT_LO 21596160u
#define OFF_COMBH  22120448u  // comb hi: [64][1024] bf16 = 32768 floats
#define OFF_COMBL  22153216u
#define WS_NEED2_F 22185984u
#define OFF_PART  OFF_G       // k_out partials alias consumed G

typedef short bf16x8 __attribute__((ext_vector_type(8)));
typedef float f32x4  __attribute__((ext_vector_type(4)));

__device__ __forceinline__ float sigm(float x){ return 1.f/(1.f+__expf(-x)); }

__device__ __forceinline__ unsigned short bf_rn(float x){
  unsigned int u = __float_as_uint(x);
  return (unsigned short)((u + 0x7fffu + ((u>>16)&1u)) >> 16);
}
__device__ __forceinline__ void split2(float x, unsigned short &h, unsigned short &l){
  h = bf_rn(x);
  float hf = __uint_as_float(((unsigned int)h)<<16);
  l = bf_rn(x - hf);
}
__device__ __forceinline__ float blo(unsigned int u){ return __uint_as_float(u<<16); }
__device__ __forceinline__ float bhi(unsigned int u){ return __uint_as_float(u & 0xffff0000u); }

// ---- one-time: transpose W=[Wx;Wh] (1536x2048) -> WT[n][k] hi/lo bf16 ----
__global__ __launch_bounds__(256) void k_wprep(const float* __restrict__ Wx,
    const float* __restrict__ Wh, unsigned short* __restrict__ wt_hi,
    unsigned short* __restrict__ wt_lo){
  __shared__ float lds[64][68];
  int bk = blockIdx.x >> 5, bn = blockIdx.x & 31;
  int k0 = bk*64, n0 = bn*64;
  int tid = threadIdx.x;
  #pragma unroll
  for (int i=0;i<4;i++){
    int flat = tid + i*256;
    int k = flat >> 4, nq = flat & 15;
    int kg = k0 + k;
    const float* srow = (kg < 1024) ? Wx + (size_t)kg*H4 : Wh + (size_t)(kg-1024)*H4;
    float4 v = *(const float4*)(srow + n0 + nq*4);
    *(float4*)&lds[k][nq*4] = v;
  }
  __syncthreads();
  #pragma unroll
  for (int i=0;i<2;i++){
    int flat = tid + i*256;
    int n = flat >> 3, k8 = flat & 7;
    ushort4 h0, h1, l0, l1;
    unsigned short h[8], l[8];
    #pragma unroll
    for (int j=0;j<8;j++) split2(lds[k8*8+j][n], h[j], l[j]);
    h0.x=h[0];h0.y=h[1];h0.z=h[2];h0.w=h[3]; h1.x=h[4];h1.y=h[5];h1.z=h[6];h1.w=h[7];
    l0.x=l[0];l0.y=l[1];l0.z=l[2];l0.w=l[3]; l1.x=l[4];l1.y=l[5];l1.z=l[6];l1.w=l[7];
    size_t dst = (size_t)(n0+n)*1536 + k0 + k8*8;
    *(ushort4*)(wt_hi+dst) = h0; *(ushort4*)(wt_hi+dst+4) = h1;
    *(ushort4*)(wt_lo+dst) = l0; *(ushort4*)(wt_lo+dst+4) = l1;
  }
}

// ---- one-time: transpose W_in (512x512) -> WIT[n][k] hi/lo bf16 ----
__global__ __launch_bounds__(256) void k_wiprep(const float* __restrict__ W_in,
    unsigned short* __restrict__ wit_hi, unsigned short* __restrict__ wit_lo){
  __shared__ float lds[64][68];
  int bk = blockIdx.x >> 3, bn = blockIdx.x & 7;
  int k0 = bk*64, n0 = bn*64;
  int tid = threadIdx.x;
  #pragma unroll
  for (int i=0;i<4;i++){
    int flat = tid + i*256;
    int k = flat >> 4, nq = flat & 15;
    float4 v = *(const float4*)(W_in + (size_t)(k0+k)*HH + n0 + nq*4);
    *(float4*)&lds[k][nq*4] = v;
  }
  __syncthreads();
  #pragma unroll
  for (int i=0;i<2;i++){
    int flat = tid + i*256;
    int n = flat >> 3, k8 = flat & 7;
    ushort4 h0, h1, l0, l1;
    unsigned short h[8], l[8];
    #pragma unroll
    for (int j=0;j<8;j++) split2(lds[k8*8+j][n], h[j], l[j]);
    h0.x=h[0];h0.y=h[1];h0.z=h[2];h0.w=h[3]; h1.x=h[4];h1.y=h[5];h1.z=h[6];h1.w=h[7];
    l0.x=l[0];l0.y=l[1];l0.z=l[2];l0.w=l[3]; l1.x=l[4];l1.y=l[5];l1.z=l[6];l1.w=l[7];
    size_t dst = (size_t)(n0+n)*HH + k0 + k8*8;
    *(ushort4*)(wit_hi+dst) = h0; *(ushort4*)(wit_hi+dst+4) = h1;
    *(ushort4*)(wit_lo+dst) = l0; *(ushort4*)(wit_lo+dst+4) = l1;
  }
}

// ---- one-time: transpose W_out (2048x512) -> WOT[n][k] hi/lo bf16 ----
__global__ __launch_bounds__(256) void k_woprep(const float* __restrict__ W_out,
    unsigned short* __restrict__ wot_hi, unsigned short* __restrict__ wot_lo){
  __shared__ float lds[64][68];
  int bk = blockIdx.x >> 3, bn = blockIdx.x & 7;   // bk 0..31, bn 0..7
  int k0 = bk*64, n0 = bn*64;
  int tid = threadIdx.x;
  #pragma unroll
  for (int i=0;i<4;i++){
    int flat = tid + i*256;
    int k = flat >> 4, nq = flat & 15;
    float4 v = *(const float4*)(W_out + (size_t)(k0+k)*HH + n0 + nq*4);
    *(float4*)&lds[k][nq*4] = v;
  }
  __syncthreads();
  #pragma unroll
  for (int i=0;i<2;i++){
    int flat = tid + i*256;
    int n = flat >> 3, k8 = flat & 7;
    ushort4 h0, h1, l0, l1;
    unsigned short h[8], l[8];
    #pragma unroll
    for (int j=0;j<8;j++) split2(lds[k8*8+j][n], h[j], l[j]);
    h0.x=h[0];h0.y=h[1];h0.z=h[2];h0.w=h[3]; h1.x=h[4];h1.y=h[5];h1.z=h[6];h1.w=h[7];
    l0.x=l[0];l0.y=l[1];l0.z=l[2];l0.w=l[3]; l1.x=l[4];l1.y=l[5];l1.z=l[6];l1.w=l[7];
    size_t dst = (size_t)(n0+n)*H4 + k0 + k8*8;
    *(ushort4*)(wot_hi+dst) = h0; *(ushort4*)(wot_hi+dst+4) = h1;
    *(ushort4*)(wot_lo+dst) = l0; *(ushort4*)(wot_lo+dst+4) = l1;
  }
}

// ---- one-time: both contexts -> bf16. grid 12800 x 256 ----
__global__ __launch_bounds__(256) void k_ctx16(const float* __restrict__ trctx,
    const float* __restrict__ txctx, unsigned short* __restrict__ ctx16){
  size_t gid = (size_t)blockIdx.x*256 + threadIdx.x;
  size_t off = gid*8;
  const size_t CH = (size_t)BB*SS*HH;
  const float* src = (off < CH) ? trctx + off : txctx + (off - CH);
  float4 a = *(const float4*)src;
  float4 c = *(const float4*)(src+4);
  ushort4 u0, u1;
  u0.x=bf_rn(a.x); u0.y=bf_rn(a.y); u0.z=bf_rn(a.z); u0.w=bf_rn(a.w);
  u1.x=bf_rn(c.x); u1.y=bf_rn(c.y); u1.z=bf_rn(c.z); u1.w=bf_rn(c.w);
  *(ushort4*)(ctx16+off) = u0;
  *(ushort4*)(ctx16+off+4) = u1;
}

// ---- one-time: embeddings -> hi/lo planes for all t ----
__global__ __launch_bounds__(128) void k_prep(const int* __restrict__ inp,
    const float* __restrict__ emb0, const float* __restrict__ wemb,
    unsigned short* __restrict__ eh, unsigned short* __restrict__ el){
  int n = blockIdx.x; int t = n >> 6, b = n & 63;
  const float* src = (t==0) ? emb0 + (size_t)b*HH
                            : wemb + (size_t)inp[b*TT + (t-1)]*HH;
  float4 v = ((const float4*)src)[threadIdx.x];
  ushort4 h, l;
  split2(v.x,h.x,l.x); split2(v.y,h.y,l.y); split2(v.z,h.z,l.z); split2(v.w,h.w,l.w);
  size_t base = ((size_t)t*BB + b)*HH + threadIdx.x*4;
  *(ushort4*)(eh+base) = h; *(ushort4*)(el+base) = l;
}

// ---- one-time: state init ----
__global__ __launch_bounds__(256) void k_init(const float* __restrict__ th0,
    const float* __restrict__ tc0, const float* __restrict__ xh0,
    const float* __restrict__ xc0, const float* __restrict__ out0,
    float* __restrict__ ws){
  unsigned short* hhp = (unsigned short*)(ws + OFF_HHP);
  unsigned short* hlp = (unsigned short*)(ws + OFF_HLP);
  unsigned short* oh  = (unsigned short*)(ws + OFF_OH);
  unsigned short* ol  = (unsigned short*)(ws + OFF_OL);
  int which = blockIdx.x >> 5;
  int idx = (blockIdx.x & 31)*256 + threadIdx.x;
  if (which==0){ ((float4*)(ws+OFF_TC))[idx] = ((const float4*)tc0)[idx]; return; }
  if (which==1){ ((float4*)(ws+OFF_XC))[idx] = ((const float4*)xc0)[idx]; return; }
  const float* s = which==2? th0 : which==3? xh0 : out0;
  float4 v = ((const float4*)s)[idx];
  ushort4 h, l;
  split2(v.x,h.x,l.x); split2(v.y,h.y,l.y); split2(v.z,h.z,l.z); split2(v.w,h.w,l.w);
  if (which==4){
    *(ushort4*)(oh + (size_t)idx*4) = h; *(ushort4*)(ol + (size_t)idx*4) = l;
  } else {
    size_t base = (size_t)(which-2)*BB*HH + (size_t)idx*4;
    *(ushort4*)(hhp+base) = h; *(ushort4*)(hlp+base) = l;
  }
}

// ---- per step: MFMA gate GEMM. grid 256 = bn(32) x ks(8), 256 thr ----
__global__ __launch_bounds__(256) void k_gemm(const unsigned short* __restrict__ wt_hi,
    const unsigned short* __restrict__ wt_lo, const unsigned short* __restrict__ eh,
    const unsigned short* __restrict__ el, const unsigned short* __restrict__ oh,
    const unsigned short* __restrict__ ol, const unsigned short* __restrict__ hhp,
    const unsigned short* __restrict__ hlp, float* __restrict__ gpart, int t){
  int tid = threadIdx.x, lane = tid & 63, wave = tid >> 6;
  int bn = blockIdx.x & 31, ks = blockIdx.x >> 5;
  int lm = lane & 15, lk = (lane >> 4) << 3;
  f32x4 acc[2][4];
  #pragma unroll
  for (int i=0;i<2;i++)
    #pragma unroll
    for (int j=0;j<4;j++) acc[i][j] = (f32x4){0.f,0.f,0.f,0.f};
  size_t ebase[2], obase[2], hbase[2];
  #pragma unroll
  for (int i=0;i<2;i++){
    int r = (wave*2 + i)*16 + lm;
    int b = r & 63, br = r >> 6;
    ebase[i] = ((size_t)t*BB + b)*HH;
    obase[i] = (size_t)b*HH;
    hbase[i] = ((size_t)br*BB + b)*HH;
  }
  size_t wb[4];
  #pragma unroll
  for (int j=0;j<4;j++) wb[j] = (size_t)(bn*64 + j*16 + lm)*1536;
  #pragma unroll
  for (int c=0;c<6;c++){
    int kc = ks*192 + c*32;
    int sec = kc >> 9;
    int kk = (kc & 511) + lk;
    const unsigned short* ph = sec==0? eh : sec==1? oh : hhp;
    const unsigned short* pl = sec==0? el : sec==1? ol : hlp;
    bf16x8 ah[2], al[2], wh_[4], wl_[4];
    #pragma unroll
    for (int i=0;i<2;i++){
      size_t off = (sec==0? ebase[i] : sec==1? obase[i] : hbase[i]) + kk;
      ah[i] = *(const bf16x8*)(ph + off);
      al[i] = *(const bf16x8*)(pl + off);
    }
    int kw = kc + lk;
    #pragma unroll
    for (int j=0;j<4;j++){
      wh_[j] = *(const bf16x8*)(wt_hi + wb[j] + kw);
      wl_[j] = *(const bf16x8*)(wt_lo + wb[j] + kw);
    }
    #pragma unroll
    for (int i=0;i<2;i++)
      #pragma unroll
      for (int j=0;j<4;j++){
        acc[i][j] = __builtin_amdgcn_mfma_f32_16x16x32_bf16(ah[i], wh_[j], acc[i][j], 0,0,0);
        acc[i][j] = __builtin_amdgcn_mfma_f32_16x16x32_bf16(ah[i], wl_[j], acc[i][j], 0,0,0);
        acc[i][j] = __builtin_amdgcn_mfma_f32_16x16x32_bf16(al[i], wh_[j], acc[i][j], 0,0,0);
      }
  }
  int lr4 = (lane >> 4) * 4;
  #pragma unroll
  for (int i=0;i<2;i++){
    int m0 = (wave*2+i)*16;
    #pragma unroll
    for (int j=0;j<4;j++){
      int col = bn*64 + j*16 + lm;
      #pragma unroll
      for (int q=0;q<4;q++){
        int row = m0 + lr4 + q;
        gpart[((size_t)ks*128 + row)*H4 + col] = acc[i][j][q];
      }
    }
  }
}

// ---- per step: 8-way partial reduce + LSTM pointwise. grid 128 x 256 ----
__global__ __launch_bounds__(256) void k_lstm(float* __restrict__ ws,
    const float* __restrict__ bias, int rs){
  int gid = blockIdx.x*256 + threadIdx.x;
  int b = gid >> 9, j = gid & 511;
  int wsl = rs ^ 1;
  const float* gp = ws + OFF_G;
  unsigned short* hhp = (unsigned short*)(ws + OFF_HHP);
  unsigned short* hlp = (unsigned short*)(ws + OFF_HLP);
  #pragma unroll
  for (int br=0;br<2;br++){
    float g0=0.f,g1=0.f,g2=0.f,g3=0.f;
    #pragma unroll
    for (int ks=0;ks<8;ks++){
      size_t base = ((size_t)ks*128 + br*64 + b)*H4 + j;
      g0 += gp[base]; g1 += gp[base+512]; g2 += gp[base+1024]; g3 += gp[base+1536];
    }
    g0 += bias[j]; g1 += bias[512+j]; g2 += bias[1024+j]; g3 += bias[1536+j];
    size_t hoff = (br? OFF_XH : OFF_TH), coff = (br? OFF_XC : OFF_TC);
    float cold = ws[coff + (size_t)rs*BB*HH + (size_t)b*HH + j];
    float cn = sigm(g1)*cold + sigm(g0)*tanhf(g2);
    float hn = sigm(g3)*tanhf(cn);
    ws[coff + (size_t)wsl*BB*HH + (size_t)b*HH + j] = cn;
    ws[hoff + (size_t)wsl*BB*HH + (size_t)b*HH + j] = hn;
    unsigned short h_, l_;
    split2(hn, h_, l_);
    hhp[(size_t)(br*64+b)*HH + j] = h_;
    hlp[(size_t)(br*64+b)*HH + j] = l_;
  }
}

// ---- per step: MFMA tgt partials = h @ W_in. grid 64 = cn(8) x ks(8) ----
__global__ __launch_bounds__(256) void k_tgtB(const unsigned short* __restrict__ wit_hi,
    const unsigned short* __restrict__ wit_lo, const unsigned short* __restrict__ hhp,
    const unsigned short* __restrict__ hlp, float* __restrict__ tgtp){
  int tid = threadIdx.x, lane = tid & 63, wave = tid >> 6;
  int cn = blockIdx.x & 7, ks = blockIdx.x >> 3;
  int lm = lane & 15, lk = (lane >> 4) << 3;
  f32x4 acc[2][4];
  #pragma unroll
  for (int i=0;i<2;i++)
    #pragma unroll
    for (int j=0;j<4;j++) acc[i][j] = (f32x4){0.f,0.f,0.f,0.f};
  size_t abase[2];
  #pragma unroll
  for (int i=0;i<2;i++) abase[i] = (size_t)(wave*32 + i*16 + lm)*HH;
  size_t wb[4];
  #pragma unroll
  for (int j=0;j<4;j++) wb[j] = (size_t)(cn*64 + j*16 + lm)*HH;
  #pragma unroll
  for (int c=0;c<2;c++){
    int kc = ks*64 + c*32;
    bf16x8 ah[2], al[2], wh_[4], wl_[4];
    #pragma unroll
    for (int i=0;i<2;i++){
      ah[i] = *(const bf16x8*)(hhp + abase[i] + kc + lk);
      al[i] = *(const bf16x8*)(hlp + abase[i] + kc + lk);
    }
    #pragma unroll
    for (int j=0;j<4;j++){
      wh_[j] = *(const bf16x8*)(wit_hi + wb[j] + kc + lk);
      wl_[j] = *(const bf16x8*)(wit_lo + wb[j] + kc + lk);
    }
    #pragma unroll
    for (int i=0;i<2;i++)
      #pragma unroll
      for (int j=0;j<4;j++){
        acc[i][j] = __builtin_amdgcn_mfma_f32_16x16x32_bf16(ah[i], wh_[j], acc[i][j], 0,0,0);
        acc[i][j] = __builtin_amdgcn_mfma_f32_16x16x32_bf16(ah[i], wl_[j], acc[i][j], 0,0,0);
        acc[i][j] = __builtin_amdgcn_mfma_f32_16x16x32_bf16(al[i], wh_[j], acc[i][j], 0,0,0);
      }
  }
  int lr4 = (lane >> 4) * 4;
  #pragma unroll
  for (int i=0;i<2;i++){
    int m0 = wave*32 + i*16;
    #pragma unroll
    for (int j=0;j<4;j++){
      int col = cn*64 + j*16 + lm;
      #pragma unroll
      for (int q=0;q<4;q++){
        int row = m0 + lr4 + q;
        tgtp[((size_t)ks*128 + row)*HH + col] = acc[i][j][q];
      }
    }
  }
}

// ---- per step: two-pass flash attention partial, 512 threads (8 waves).
// grid 1024: sh=blk&7, b=(blk>>3)&63, branch=blk>>9. Each block: 50 s-rows.
// __launch_bounds__(512,8): VGPR<=64 -> 4 blocks/CU -> 100% wave occupancy.
__global__ __launch_bounds__(512, 8) void k_attn(const float* __restrict__ tree_ctx,
    const float* __restrict__ text_ctx, const unsigned short* __restrict__ ctx16,
    float* __restrict__ ws, int use16){
  int blk = blockIdx.x;
  int sh = blk & 7, b = (blk>>3) & 63, branch = blk >> 9;
  int tid = threadIdx.x, lane = tid & 63, wave = tid >> 6;
  __shared__ float tgt_s[512];
  __shared__ float sc_s[64];
  __shared__ float w_s[64];
  __shared__ float accs[8][512];    // 16 KB: per-wave column partials
  int row128 = branch*64 + b;
  if (tid < 128){
    float4 s = {0,0,0,0};
    #pragma unroll
    for (int p=0;p<8;p++){
      float4 v = *(const float4*)(ws + OFF_TGTP + ((size_t)p*128 + row128)*HH + tid*4);
      s.x += v.x; s.y += v.y; s.z += v.z; s.w += v.w;
    }
    ((float4*)tgt_s)[tid] = s;
  }
  if (tid >= 128 && tid < 192) sc_s[tid-128] = -INFINITY;
  __syncthreads();
  const size_t CH = (size_t)BB*SS*HH;
  const float* ctxf = (branch? text_ctx : tree_ctx) + ((size_t)b*SS + sh*50)*HH;
  const unsigned short* c16 = ctx16 + (branch? CH:0) + ((size_t)b*SS + sh*50)*HH;
  // pass 1: scores; rows strided by 8 waves, one coalesced 1KB row per wave-iter
  float4 ta = *(const float4*)&tgt_s[lane*8];
  float4 tb = *(const float4*)&tgt_s[lane*8+4];
  if (use16){
    for (int r = wave; r < 50; r += 8){
      uint4 u = *(const uint4*)(c16 + (size_t)r*HH + lane*8);
      float p = blo(u.x)*ta.x + bhi(u.x)*ta.y + blo(u.y)*ta.z + bhi(u.y)*ta.w
              + blo(u.z)*tb.x + bhi(u.z)*tb.y + blo(u.w)*tb.z + bhi(u.w)*tb.w;
      #pragma unroll
      for (int off=32; off; off>>=1) p += __shfl_xor(p, off, 64);
      if (lane==0) sc_s[r] = p;
    }
  } else {
    for (int r = wave; r < 50; r += 8){
      const float* crow = ctxf + (size_t)r*HH + lane*8;
      float4 ca = *(const float4*)crow;
      float4 cb = *(const float4*)(crow+4);
      float p = ca.x*ta.x + ca.y*ta.y + ca.z*ta.z + ca.w*ta.w
              + cb.x*tb.x + cb.y*tb.y + cb.z*tb.z + cb.w*tb.w;
      #pragma unroll
      for (int off=32; off; off>>=1) p += __shfl_xor(p, off, 64);
      if (lane==0) sc_s[r] = p;
    }
  }
  __syncthreads();
  // wave 0: softmax partial (m, l), unnormalized weights -> LDS
  if (wave==0){
    float s = sc_s[lane];
    float m = s;
    #pragma unroll
    for (int off=32; off; off>>=1) m = fmaxf(m, __shfl_xor(m, off, 64));
    float e = (lane<50)? __expf(s-m) : 0.f;
    w_s[lane] = e;
    float l = e;
    #pragma unroll
    for (int off=32; off; off>>=1) l += __shfl_xor(l, off, 64);
    if (lane==0){
      int pidx = (branch*64 + b)*8 + sh;
      ws[OFF_PML + (size_t)pidx*2]   = m;
      ws[OFF_PML + (size_t)pidx*2+1] = l;
    }
  }
  __syncthreads();
  // pass 2: each wave accumulates all 512 cols (lane owns 8) over its rows
  float a[8] = {0,0,0,0,0,0,0,0};
  if (use16){
    for (int r = wave; r < 50; r += 8){
      float w = w_s[r];
      uint4 u = *(const uint4*)(c16 + (size_t)r*HH + lane*8);
      a[0] += w*blo(u.x); a[1] += w*bhi(u.x);
      a[2] += w*blo(u.y); a[3] += w*bhi(u.y);
      a[4] += w*blo(u.z); a[5] += w*bhi(u.z);
      a[6] += w*blo(u.w); a[7] += w*bhi(u.w);
    }
  } else {
    for (int r = wave; r < 50; r += 8){
      float w = w_s[r];
      const float* crow = ctxf + (size_t)r*HH + lane*8;
      float4 ca = *(const float4*)crow;
      float4 cb = *(const float4*)(crow+4);
      a[0] += w*ca.x; a[1] += w*ca.y; a[2] += w*ca.z; a[3] += w*ca.w;
      a[4] += w*cb.x; a[5] += w*cb.y; a[6] += w*cb.z; a[7] += w*cb.w;
    }
  }
  #pragma unroll
  for (int j=0;j<8;j++) accs[wave][lane*8+j] = a[j];
  __syncthreads();
  // column reduce across the 8 waves; 512 threads = 1 col each
  float s = 0.f;
  #pragma unroll
  for (int w8=0;w8<8;w8++) s += accs[w8][tid];
  int pidx = (branch*64 + b)*8 + sh;
  ws[OFF_PACC + (size_t)pidx*HH + tid] = s;
}

// ---- per step: merge attn partials -> comb hi/lo bf16 [64][1024]. grid 64 ----
__global__ __launch_bounds__(256) void k_outA(float* __restrict__ ws){
  __shared__ float ce_s[2][8];
  int b = blockIdx.x, tid = threadIdx.x;
  if (tid < 2){
    int p0 = (tid*64 + b)*8;
    float mv[8], lv[8];
    float M = -INFINITY;
    #pragma unroll
    for (int i=0;i<8;i++){
      mv[i] = ws[OFF_PML + (size_t)(p0+i)*2];
      lv[i] = ws[OFF_PML + (size_t)(p0+i)*2+1];
      M = fmaxf(M, mv[i]);
    }
    float L = 0.f, ev[8];
    #pragma unroll
    for (int i=0;i<8;i++){ ev[i] = __expf(mv[i]-M); L += lv[i]*ev[i]; }
    #pragma unroll
    for (int i=0;i<8;i++) ce_s[tid][i] = ev[i]/L;
  }
  __syncthreads();
  int h = tid*4;                 // 0..1023
  int sec = h >> 9, hs = h & 511;
  int p0 = (sec*64 + b)*8;
  float4 v = {0,0,0,0};
  #pragma unroll
  for (int p=0;p<8;p++){
    float4 a = *(const float4*)(ws + OFF_PACC + (size_t)(p0+p)*HH + hs);
    float cw = ce_s[sec][p];
    v.x += a.x*cw; v.y += a.y*cw; v.z += a.z*cw; v.w += a.w*cw;
  }
  ushort4 hv, lv;
  split2(v.x,hv.x,lv.x); split2(v.y,hv.y,lv.y); split2(v.z,hv.z,lv.z); split2(v.w,hv.w,lv.w);
  unsigned short* ch = (unsigned short*)(ws + OFF_COMBH);
  unsigned short* cl = (unsigned short*)(ws + OFF_COMBL);
  *(ushort4*)(ch + (size_t)b*1024 + h) = hv;
  *(ushort4*)(cl + (size_t)b*1024 + h) = lv;
}

// ---- per step: MFMA out partials = comb @ W_out. grid 64 = nt(8) x ks(8) ----
__global__ __launch_bounds__(256) void k_outBm(const unsigned short* __restrict__ wot_hi,
    const unsigned short* __restrict__ wot_lo, const unsigned short* __restrict__ combh,
    const unsigned short* __restrict__ combl, const unsigned short* __restrict__ hhp,
    const unsigned short* __restrict__ hlp, float* __restrict__ part){
  int tid = threadIdx.x, lane = tid & 63, wave = tid >> 6;
  int nt = blockIdx.x & 7, ks = blockIdx.x >> 3;
  int lm = lane & 15, lk = (lane >> 4) << 3;
  f32x4 acc[4];
  #pragma unroll
  for (int m=0;m<4;m++) acc[m] = (f32x4){0.f,0.f,0.f,0.f};
  size_t wb = (size_t)(nt*64 + wave*16 + lm)*H4;
  #pragma unroll
  for (int c=0;c<8;c++){
    int kg = ks*256 + c*32;
    int sec = kg >> 9;                 // 0,1: comb planes; 2,3: th/xh planes
    bf16x8 wh_ = *(const bf16x8*)(wot_hi + wb + kg + lk);
    bf16x8 wl_ = *(const bf16x8*)(wot_lo + wb + kg + lk);
    #pragma unroll
    for (int m=0;m<4;m++){
      int row = m*16 + lm;             // batch b 0..63
      bf16x8 ah, al;
      if (sec < 2){
        size_t off = (size_t)row*1024 + kg + lk;
        ah = *(const bf16x8*)(combh + off);
        al = *(const bf16x8*)(combl + off);
      } else {
        size_t off = ((size_t)(sec-2)*64 + row)*HH + (kg & 511) + lk;
        ah = *(const bf16x8*)(hhp + off);
        al = *(const bf16x8*)(hlp + off);
      }
      acc[m] = __builtin_amdgcn_mfma_f32_16x16x32_bf16(ah, wh_, acc[m], 0,0,0);
      acc[m] = __builtin_amdgcn_mfma_f32_16x16x32_bf16(ah, wl_, acc[m], 0,0,0);
      acc[m] = __builtin_amdgcn_mfma_f32_16x16x32_bf16(al, wh_, acc[m], 0,0,0);
    }
  }
  int lr4 = (lane >> 4) * 4;
  int col = nt*64 + wave*16 + lm;
  #pragma unroll
  for (int m=0;m<4;m++){
    #pragma unroll
    for (int q=0;q<4;q++){
      int b = m*16 + lr4 + q;
      part[((size_t)ks*BB + b)*HH + col] = acc[m][q];
    }
  }
}

// ---- per step (fallback): fp32 split-K GEMM out = combined @ W_out. grid 256 ----
__global__ __launch_bounds__(256) void k_outB(const float* __restrict__ W_out,
    float* __restrict__ ws, int wsl){
  __shared__ float comb_s[16][256];
  __shared__ float ce_s[16][8];
  int tid = threadIdx.x, lane = tid & 63, wave = tid >> 6;
  int blk = blockIdx.x;
  int ct = blk & 7, bg = (blk>>3)&3, ks = blk>>5;
  int b0 = bg*16;
  int k0 = ks*256;
  int sec = ks >> 1;
  int kk0 = (ks & 1)*256;
  int c = ct*64 + lane;
  if (sec < 2){
    if (tid < 16){
      int b = b0 + tid;
      int p0 = (sec*64 + b)*8;
      float mv[8], lv[8];
      float M = -INFINITY;
      #pragma unroll
      for (int i=0;i<8;i++){
        mv[i] = ws[OFF_PML + (size_t)(p0+i)*2];
        lv[i] = ws[OFF_PML + (size_t)(p0+i)*2+1];
        M = fmaxf(M, mv[i]);
      }
      float L = 0.f, ev[8];
      #pragma unroll
      for (int i=0;i<8;i++){ ev[i] = __expf(mv[i]-M); L += lv[i]*ev[i]; }
      #pragma unroll
      for (int i=0;i<8;i++) ce_s[tid][i] = ev[i]/L;
    }
    __syncthreads();
  }
  #pragma unroll
  for (int i=0;i<4;i++){
    int flat = tid + i*256;
    int row = flat >> 6;
    int q   = flat & 63;
    int b = b0 + row;
    int h = kk0 + q*4;
    float4 v;
    if (sec < 2){
      int p0 = (sec*64 + b)*8;
      v.x = 0.f; v.y = 0.f; v.z = 0.f; v.w = 0.f;
      #pragma unroll
      for (int p=0;p<8;p++){
        float4 a = *(const float4*)(ws + OFF_PACC + (size_t)(p0+p)*HH + h);
        float cw = ce_s[row][p];
        v.x += a.x*cw; v.y += a.y*cw; v.z += a.z*cw; v.w += a.w*cw;
      }
    } else {
      size_t hoff = (sec==2 ? OFF_TH : OFF_XH) + (size_t)wsl*BB*HH;
      v = *(const float4*)(ws + hoff + (size_t)b*HH + h);
    }
    *(float4*)&comb_s[row][q*4] = v;
  }
  __syncthreads();
  float acc[4] = {0,0,0,0};
  #pragma unroll 4
  for (int k=0;k<256;k++){
    float wv = W_out[(size_t)(k0+k)*HH + c];
    #pragma unroll
    for (int i=0;i<4;i++) acc[i] += comb_s[wave*4+i][k]*wv;
  }
  #pragma unroll
  for (int i=0;i<4;i++){
    int b = b0 + wave*4 + i;
    ws[OFF_PART + ((size_t)ks*BB + b)*HH + c] = acc[i];
  }
}

// ---- per step: reduce 8 partials + tanh + store + O planes. grid 32 x 256 ----
__global__ __launch_bounds__(256) void k_outC(float* __restrict__ ws,
    float* __restrict__ dout, int t){
  int gid = blockIdx.x*256 + threadIdx.x;
  int b = gid >> 7, cq = gid & 127;
  int c0 = cq*4;
  float4 s = {0,0,0,0};
  #pragma unroll
  for (int ks=0;ks<8;ks++){
    float4 p = *(const float4*)(ws + OFF_PART + ((size_t)ks*BB + b)*HH + c0);
    s.x += p.x; s.y += p.y; s.z += p.z; s.w += p.w;
  }
  float4 o;
  o.x = tanhf(s.x); o.y = tanhf(s.y); o.z = tanhf(s.z); o.w = tanhf(s.w);
  *(float4*)(dout + ((size_t)b*TT + t)*HH + c0) = o;
  ushort4 h, l;
  split2(o.x,h.x,l.x); split2(o.y,h.y,l.y); split2(o.z,h.z,l.z); split2(o.w,h.w,l.w);
  unsigned short* oh = (unsigned short*)(ws + OFF_OH);
  unsigned short* ol = (unsigned short*)(ws + OFF_OL);
  *(ushort4*)(oh + (size_t)b*HH + c0) = h;
  *(ushort4*)(ol + (size_t)b*HH + c0) = l;
}

extern "C" void kernel_launch(void* const* d_in, const int* in_sizes, int n_in,
                              void* d_out, int out_size, void* d_ws, size_t ws_size,
                              hipStream_t stream){
  const int*   inp   = (const int*)  d_in[0];
  const float* emb0  = (const float*)d_in[1];
  const float* out0  = (const float*)d_in[2];
  const float* th0   = (const float*)d_in[3];
  const float* tc0   = (const float*)d_in[4];
  const float* trctx = (const float*)d_in[5];
  const float* xh0   = (const float*)d_in[6];
  const float* xc0   = (const float*)d_in[7];
  const float* txctx = (const float*)d_in[8];
  const float* wemb  = (const float*)d_in[9];
  const float* Wx    = (const float*)d_in[10];
  const float* Wh    = (const float*)d_in[11];
  const float* bias  = (const float*)d_in[12];
  const float* W_in  = (const float*)d_in[13];
  const float* W_out = (const float*)d_in[14];
  float* ws  = (float*)d_ws;
  float* out = (float*)d_out;
  unsigned short* wt_hi = (unsigned short*)(ws + OFF_WT_HI);
  unsigned short* wt_lo = (unsigned short*)(ws + OFF_WT_LO);
  unsigned short* wit_hi = (unsigned short*)(ws + OFF_WIT_HI);
  unsigned short* wit_lo = (unsigned short*)(ws + OFF_WIT_LO);
  unsigned short* wot_hi = (unsigned short*)(ws + OFF_WOT_HI);
  unsigned short* wot_lo = (unsigned short*)(ws + OFF_WOT_LO);
  unsigned short* combh = (unsigned short*)(ws + OFF_COMBH);
  unsigned short* combl = (unsigned short*)(ws + OFF_COMBL);
  unsigned short* eh = (unsigned short*)(ws + OFF_EH);
  unsigned short* el = (unsigned short*)(ws + OFF_EL);
  unsigned short* oh = (unsigned short*)(ws + OFF_OH);
  unsigned short* ol = (unsigned short*)(ws + OFF_OL);
  unsigned short* hhp = (unsigned short*)(ws + OFF_HHP);
  unsigned short* hlp = (unsigned short*)(ws + OFF_HLP);
  unsigned short* ctx16 = (unsigned short*)(ws + OFF_CTX16);
  float* gpart = ws + OFF_G;
  float* tgtp  = ws + OFF_TGTP;
  float* part  = ws + OFF_PART;
  int use16 = (ws_size >= (size_t)WS_NEED_F  * 4u) ? 1 : 0;
  int useMf = (ws_size >= (size_t)WS_NEED2_F * 4u) ? 1 : 0;

  hipLaunchKernelGGL(k_wprep,  dim3(768),   dim3(256), 0, stream, Wx, Wh, wt_hi, wt_lo);
  hipLaunchKernelGGL(k_wiprep, dim3(64),    dim3(256), 0, stream, W_in, wit_hi, wit_lo);
  if (useMf)
    hipLaunchKernelGGL(k_woprep, dim3(256), dim3(256), 0, stream, W_out, wot_hi, wot_lo);
  if (use16)
    hipLaunchKernelGGL(k_ctx16, dim3(12800), dim3(256), 0, stream, trctx, txctx, ctx16);
  hipLaunchKernelGGL(k_prep,   dim3(TT*BB), dim3(128), 0, stream, inp, emb0, wemb, eh, el);
  hipLaunchKernelGGL(k_init,   dim3(160),   dim3(256), 0, stream, th0, tc0, xh0, xc0, out0, ws);
  for (int t=0; t<TT; t++){
    int rs = t & 1, wsl = rs ^ 1;
    hipLaunchKernelGGL(k_gemm, dim3(256),  dim3(256), 0, stream,
                       wt_hi, wt_lo, eh, el, oh, ol, hhp, hlp, gpart, t);
    hipLaunchKernelGGL(k_lstm, dim3(128),  dim3(256), 0, stream, ws, bias, rs);
    hipLaunchKernelGGL(k_tgtB, dim3(64),   dim3(256), 0, stream, wit_hi, wit_lo, hhp, hlp, tgtp);
    hipLaunchKernelGGL(k_attn, dim3(1024), dim3(512), 0, stream, trctx, txctx, ctx16, ws, use16);
    if (useMf){
      hipLaunchKernelGGL(k_outA,  dim3(64), dim3(256), 0, stream, ws);
      hipLaunchKernelGGL(k_outBm, dim3(64), dim3(256), 0, stream,
                         wot_hi, wot_lo, combh, combl, hhp, hlp, part);
    } else {
      hipLaunchKernelGGL(k_outB, dim3(256), dim3(256), 0, stream, W_out, ws, wsl);
    }
    hipLaunchKernelGGL(k_outC, dim3(32),   dim3(256), 0, stream, ws, out, t);
  }
}